// Round 1
// baseline (3978.322 us; speedup 1.0000x reference)
//
#include <hip/hip_runtime.h>
#include <hip/hip_bf16.h>

// HybridBridge: B=8, L=4096, D=512, C=256, T=2, H=2, HD=256, Hc=512, H2=1024
// N = B*L = 32768 token rows.
//
// Pipeline (all on stream):
//  1. ctx_kernel      : per-batch tiny GEMMs -> gb1(=1+gamma), beta, gate, k, v
//  2. foldq_kernel    : fold q_ln gain/bias into wq -> wq', bq'
//  3. stats_kernel    : per-row mean/rstd of x (shared by film-LN and q-LN)
//  4. gemm<CONCAT>    : relu([x,ctx] @ concat_w.T + b) -> bufc (bf16)
//  5. lnrows_kernel   : LN(bufc) in place -> upd_c
//  6. gemm<XHAT>      : xhat @ wq'.T + bq' -> bufq (q)
//  7. attn_kernel     : 2-token softmax attention -> bufa (a)
//  8. gemm<BF16>      : a @ out_proj.T + b -> bufq (attn_out, reuse)
//  9. gemm<MIX>       : relu([x,ao,x-ao,x*ao] @ mix_w1.T + b) -> bufh
// 10. gemm<BF16>      : h1 @ mix_w2.T + b -> bufa (upd_a, reuse)
// 11. final_kernel    : LN(base + gate*mask*(upd_c+upd_a)) -> d_out (f32)
//
// Workspace: ~169 MB (bf16 intermediates; 2% absmax threshold tolerates this).

#define N_TOK 32768
#define DD 512

typedef __hip_bfloat16 bf16;

__device__ __forceinline__ float bf2f(unsigned int h) {
    return __uint_as_float(h << 16);
}
__device__ __forceinline__ unsigned short f2bf(float f) {
    unsigned int u = __float_as_uint(f);
    u += 0x7FFFu + ((u >> 16) & 1u);   // round-to-nearest-even
    return (unsigned short)(u >> 16);
}
__device__ __forceinline__ void load8_bf16(const bf16* p, float* v) {
    uint4 u = *(const uint4*)p;
    v[0] = bf2f(u.x & 0xffffu); v[1] = bf2f(u.x >> 16);
    v[2] = bf2f(u.y & 0xffffu); v[3] = bf2f(u.y >> 16);
    v[4] = bf2f(u.z & 0xffffu); v[5] = bf2f(u.z >> 16);
    v[6] = bf2f(u.w & 0xffffu); v[7] = bf2f(u.w >> 16);
}
__device__ __forceinline__ void store8_bf16(bf16* p, const float* v) {
    uint4 u;
    u.x = (unsigned)f2bf(v[0]) | ((unsigned)f2bf(v[1]) << 16);
    u.y = (unsigned)f2bf(v[2]) | ((unsigned)f2bf(v[3]) << 16);
    u.z = (unsigned)f2bf(v[4]) | ((unsigned)f2bf(v[5]) << 16);
    u.w = (unsigned)f2bf(v[6]) | ((unsigned)f2bf(v[7]) << 16);
    *(uint4*)p = u;
}

// ---- dot of a global f32 row with an LDS vector -------------------------
__device__ __forceinline__ float dotw(const float* __restrict__ w,
                                      const float* __restrict__ s, int n) {
    float acc = 0.f;
    for (int i = 0; i < n; i += 4) {
        float4 wv = *(const float4*)(w + i);
        acc += wv.x * s[i] + wv.y * s[i+1] + wv.z * s[i+2] + wv.w * s[i+3];
    }
    return acc;
}

// ==== 1. per-batch context kernel ========================================
__global__ void ctx_kernel(const float* __restrict__ context,
                           const float* __restrict__ film_w, const float* __restrict__ film_b,
                           const float* __restrict__ gate_w, const float* __restrict__ gate_b,
                           const float* __restrict__ ctx_w1, const float* __restrict__ ctx_b1,
                           const float* __restrict__ ctx_w2, const float* __restrict__ ctx_b2,
                           const float* __restrict__ in_proj_w, const float* __restrict__ in_proj_b,
                           float* __restrict__ gb1, float* __restrict__ betab,
                           float* __restrict__ gateb,
                           float* __restrict__ kbuf, float* __restrict__ vbuf) {
    const int b = blockIdx.x;
    const int tid = threadIdx.x;
    __shared__ float s_ctx[256];
    __shared__ float s_h[512];
    __shared__ float s_tok[1024];
    s_ctx[tid] = context[b * 256 + tid];
    __syncthreads();
    #pragma unroll
    for (int rep = 0; rep < 2; rep++) {
        int j = tid + rep * 256;
        float g  = dotw(film_w + (size_t)j * 256, s_ctx, 256) + film_b[j];
        float be = dotw(film_w + (size_t)(512 + j) * 256, s_ctx, 256) + film_b[512 + j];
        float gt = dotw(gate_w + (size_t)j * 256, s_ctx, 256) + gate_b[j];
        float hv = dotw(ctx_w1 + (size_t)j * 256, s_ctx, 256) + ctx_b1[j];
        gb1[b * 512 + j]   = 1.0f + g;                      // film_gain = 1
        betab[b * 512 + j] = be;
        gateb[b * 512 + j] = 1.f / (1.f + expf(-gt));       // alpha_max = 1
        s_h[j] = 0.5f * hv * (1.0f + erff(hv * 0.70710678118654752f)); // exact gelu
    }
    __syncthreads();
    #pragma unroll
    for (int rep = 0; rep < 4; rep++) {
        int j = tid + rep * 256;  // 0..1023
        s_tok[j] = dotw(ctx_w2 + (size_t)j * 512, s_h, 512) + ctx_b2[j];
    }
    __syncthreads();
    #pragma unroll
    for (int t = 0; t < 2; t++) {
        #pragma unroll
        for (int rep = 0; rep < 2; rep++) {
            int j = tid + rep * 256;
            float kk = dotw(in_proj_w + (size_t)(512 + j) * 512,  s_tok + t * 512, 512) + in_proj_b[512 + j];
            float vv = dotw(in_proj_w + (size_t)(1024 + j) * 512, s_tok + t * 512, 512) + in_proj_b[1024 + j];
            kbuf[(b * 2 + t) * 512 + j] = kk;
            vbuf[(b * 2 + t) * 512 + j] = vv;
        }
    }
}

// ==== 2. fold q-LN affine into wq ========================================
__global__ void foldq_kernel(const float* __restrict__ in_proj_w,
                             const float* __restrict__ in_proj_b,
                             const float* __restrict__ qg, const float* __restrict__ qb,
                             float* __restrict__ wqp, float* __restrict__ bqp) {
    const int j = blockIdx.x;
    const int tid = threadIdx.x;
    __shared__ float red[256];
    float part = 0.f;
    #pragma unroll
    for (int rep = 0; rep < 2; rep++) {
        int i = tid + rep * 256;
        float w = in_proj_w[(size_t)j * 512 + i];
        wqp[(size_t)j * 512 + i] = w * qg[i];
        part += w * qb[i];
    }
    red[tid] = part;
    __syncthreads();
    for (int s = 128; s > 0; s >>= 1) {
        if (tid < s) red[tid] += red[tid + s];
        __syncthreads();
    }
    if (tid == 0) bqp[j] = in_proj_b[j] + red[0];
}

// ==== 3. per-row mean/rstd of x ==========================================
__global__ void stats_kernel(const float* __restrict__ x, float* __restrict__ stats) {
    const int wave = threadIdx.x >> 6, lane = threadIdx.x & 63;
    const long row = (long)blockIdx.x * 4 + wave;
    const float* xr = x + row * DD + lane * 8;
    float4 v0 = *(const float4*)xr;
    float4 v1 = *(const float4*)(xr + 4);
    float s  = v0.x + v0.y + v0.z + v0.w + v1.x + v1.y + v1.z + v1.w;
    float ss = v0.x*v0.x + v0.y*v0.y + v0.z*v0.z + v0.w*v0.w
             + v1.x*v1.x + v1.y*v1.y + v1.z*v1.z + v1.w*v1.w;
    for (int m = 1; m < 64; m <<= 1) { s += __shfl_xor(s, m, 64); ss += __shfl_xor(ss, m, 64); }
    float mean = s * (1.f / 512.f);
    float var  = ss * (1.f / 512.f) - mean * mean;
    if (lane == 0) { stats[row * 2] = mean; stats[row * 2 + 1] = rsqrtf(var + 1e-5f); }
}

// ==== generic tiled GEMM: out = act(A @ W.T + bias), A built by MODE =====
// MODE 0: A=[x | ctx]  (K=768)
// MODE 1: A=xhat ((x-mean)*rstd on the fly, K=512)
// MODE 2: A=abf (bf16 buffer, K template)
// MODE 3: A=[x | ao | x-ao | x*ao] (K=2048, ao=abf)
template<int MODE, bool RELU, int K>
__launch_bounds__(256)
__global__ void gemm_kernel(const float* __restrict__ xptr,
                            const float* __restrict__ ctx,
                            const float* __restrict__ stats,
                            const bf16* __restrict__ abf,
                            const float* __restrict__ W,
                            const float* __restrict__ bias,
                            bf16* __restrict__ out,
                            const int Dout) {
    __shared__ float As[16][68];   // [k][m], +4 pad keeps float4 rows 16B-aligned
    __shared__ float Ws[16][68];   // [k][n]
    const int tid  = threadIdx.x;
    const int arow = tid >> 2;          // 0..63 : tile row (A) / tile col (W) staged
    const int kg   = (tid & 3) << 2;    // 0,4,8,12 : k sub-group
    const long grow = (long)blockIdx.x * 64 + arow;
    const long gcol = (long)blockIdx.y * 64 + arow;
    const int tr = tid >> 4;            // 0..15
    const int tc = tid & 15;

    float mean = 0.f, rstd = 0.f;
    if (MODE == 1) { mean = stats[grow * 2]; rstd = stats[grow * 2 + 1]; }
    const int bidx = (int)(grow >> 12); // batch = row / 4096

    float acc[4][4];
    #pragma unroll
    for (int i = 0; i < 4; i++)
        #pragma unroll
        for (int j = 0; j < 4; j++) acc[i][j] = 0.f;

    for (int k0 = 0; k0 < K; k0 += 16) {
        const int k = k0 + kg;
        float a4[4];
        if constexpr (MODE == 0) {
            if (k < 512) {
                float4 v = *(const float4*)(xptr + grow * 512 + k);
                a4[0] = v.x; a4[1] = v.y; a4[2] = v.z; a4[3] = v.w;
            } else {
                float4 v = *(const float4*)(ctx + bidx * 256 + (k - 512));
                a4[0] = v.x; a4[1] = v.y; a4[2] = v.z; a4[3] = v.w;
            }
        } else if constexpr (MODE == 1) {
            float4 v = *(const float4*)(xptr + grow * 512 + k);
            a4[0] = (v.x - mean) * rstd; a4[1] = (v.y - mean) * rstd;
            a4[2] = (v.z - mean) * rstd; a4[3] = (v.w - mean) * rstd;
        } else if constexpr (MODE == 2) {
            uint2 u = *(const uint2*)(abf + grow * K + k);
            a4[0] = bf2f(u.x & 0xffffu); a4[1] = bf2f(u.x >> 16);
            a4[2] = bf2f(u.y & 0xffffu); a4[3] = bf2f(u.y >> 16);
        } else { // MODE 3
            const int seg = k >> 9;
            const int k2  = k & 511;
            if (seg == 0) {
                float4 v = *(const float4*)(xptr + grow * 512 + k2);
                a4[0] = v.x; a4[1] = v.y; a4[2] = v.z; a4[3] = v.w;
            } else if (seg == 1) {
                uint2 u = *(const uint2*)(abf + grow * 512 + k2);
                a4[0] = bf2f(u.x & 0xffffu); a4[1] = bf2f(u.x >> 16);
                a4[2] = bf2f(u.y & 0xffffu); a4[3] = bf2f(u.y >> 16);
            } else {
                float4 v = *(const float4*)(xptr + grow * 512 + k2);
                uint2 u = *(const uint2*)(abf + grow * 512 + k2);
                float o0 = bf2f(u.x & 0xffffu), o1 = bf2f(u.x >> 16);
                float o2 = bf2f(u.y & 0xffffu), o3 = bf2f(u.y >> 16);
                if (seg == 2) { a4[0] = v.x - o0; a4[1] = v.y - o1; a4[2] = v.z - o2; a4[3] = v.w - o3; }
                else          { a4[0] = v.x * o0; a4[1] = v.y * o1; a4[2] = v.z * o2; a4[3] = v.w * o3; }
            }
        }
        float4 wv = *(const float4*)(W + gcol * K + k);

        __syncthreads();   // previous tile fully consumed
        As[kg + 0][arow] = a4[0]; As[kg + 1][arow] = a4[1];
        As[kg + 2][arow] = a4[2]; As[kg + 3][arow] = a4[3];
        Ws[kg + 0][arow] = wv.x;  Ws[kg + 1][arow] = wv.y;
        Ws[kg + 2][arow] = wv.z;  Ws[kg + 3][arow] = wv.w;
        __syncthreads();

        #pragma unroll
        for (int kk = 0; kk < 16; kk++) {
            float4 av = *(const float4*)&As[kk][tr << 2];
            float4 bv = *(const float4*)&Ws[kk][tc << 2];
            float aa[4] = {av.x, av.y, av.z, av.w};
            float bb[4] = {bv.x, bv.y, bv.z, bv.w};
            #pragma unroll
            for (int i = 0; i < 4; i++)
                #pragma unroll
                for (int j = 0; j < 4; j++) acc[i][j] += aa[i] * bb[j];
        }
    }

    const long orow = (long)blockIdx.x * 64 + (tr << 2);
    const int  ocol = blockIdx.y * 64 + (tc << 2);
    float bv4[4] = {bias[ocol], bias[ocol + 1], bias[ocol + 2], bias[ocol + 3]};
    #pragma unroll
    for (int i = 0; i < 4; i++) {
        float o[4];
        #pragma unroll
        for (int j = 0; j < 4; j++) {
            float v = acc[i][j] + bv4[j];
            if (RELU) v = fmaxf(v, 0.f);
            o[j] = v;
        }
        uint2 u;
        u.x = (unsigned)f2bf(o[0]) | ((unsigned)f2bf(o[1]) << 16);
        u.y = (unsigned)f2bf(o[2]) | ((unsigned)f2bf(o[3]) << 16);
        *(uint2*)(out + (orow + i) * (long)Dout + ocol) = u;
    }
}

// ==== 5. row LayerNorm on a bf16 buffer (in place) =======================
__global__ void lnrows_kernel(bf16* __restrict__ buf,
                              const float* __restrict__ g, const float* __restrict__ b) {
    const int wave = threadIdx.x >> 6, lane = threadIdx.x & 63;
    const long row = (long)blockIdx.x * 4 + wave;
    bf16* p = buf + row * DD + lane * 8;
    float v[8];
    load8_bf16(p, v);
    float s = 0.f, ss = 0.f;
    #pragma unroll
    for (int e = 0; e < 8; e++) { s += v[e]; ss += v[e] * v[e]; }
    for (int m = 1; m < 64; m <<= 1) { s += __shfl_xor(s, m, 64); ss += __shfl_xor(ss, m, 64); }
    float mean = s * (1.f / 512.f);
    float rstd = rsqrtf(ss * (1.f / 512.f) - mean * mean + 1e-5f);
    float o[8];
    #pragma unroll
    for (int e = 0; e < 8; e++) {
        int c = lane * 8 + e;
        o[e] = (v[e] - mean) * rstd * g[c] + b[c];
    }
    store8_bf16(p, o);
}

// ==== 7. tiny attention: T=2 tokens, H=2 heads, HD=256 ===================
__global__ void attn_kernel(const bf16* __restrict__ qbuf,
                            const float* __restrict__ kbuf, const float* __restrict__ vbuf,
                            bf16* __restrict__ abuf) {
    const int wave = threadIdx.x >> 6, lane = threadIdx.x & 63;
    const long row = (long)blockIdx.x * 4 + wave;
    const int b = (int)(row >> 12);
    const int h = lane >> 5;
    const int off = h * 256 + (lane & 31) * 8;
    float q[8];
    load8_bf16(qbuf + row * DD + off, q);
    const float* k0 = kbuf + (b * 2 + 0) * 512 + off;
    const float* k1 = kbuf + (b * 2 + 1) * 512 + off;
    float s0 = 0.f, s1 = 0.f;
    #pragma unroll
    for (int e = 0; e < 8; e++) { s0 += q[e] * k0[e]; s1 += q[e] * k1[e]; }
    for (int m = 1; m < 32; m <<= 1) { s0 += __shfl_xor(s0, m, 64); s1 += __shfl_xor(s1, m, 64); }
    s0 *= (1.f / 16.f); s1 *= (1.f / 16.f);   // / sqrt(HD=256)
    float mx = fmaxf(s0, s1);
    float e0 = expf(s0 - mx), e1 = expf(s1 - mx);
    float inv = 1.f / (e0 + e1);
    float p0 = e0 * inv, p1 = e1 * inv;
    const float* v0 = vbuf + (b * 2 + 0) * 512 + off;
    const float* v1 = vbuf + (b * 2 + 1) * 512 + off;
    float a[8];
    #pragma unroll
    for (int e = 0; e < 8; e++) a[e] = p0 * v0[e] + p1 * v1[e];
    store8_bf16(abuf + row * DD + off, a);
}

// ==== 11. final: base + gate*mask*(upd_c+upd_a), then out-LN =============
__global__ void final_kernel(const float* __restrict__ x, const float* __restrict__ stats,
                             const bf16* __restrict__ updc, const bf16* __restrict__ upda,
                             const float* __restrict__ gb1, const float* __restrict__ betab,
                             const float* __restrict__ gateb, const int* __restrict__ mask,
                             const float* __restrict__ fg, const float* __restrict__ fb,
                             const float* __restrict__ og, const float* __restrict__ ob,
                             float* __restrict__ out) {
    const int wave = threadIdx.x >> 6, lane = threadIdx.x & 63;
    const long row = (long)blockIdx.x * 4 + wave;
    const int b = (int)(row >> 12);
    const int c0 = lane * 8;
    float4 xv0 = *(const float4*)(x + row * DD + c0);
    float4 xv1 = *(const float4*)(x + row * DD + c0 + 4);
    float xv[8] = {xv0.x, xv0.y, xv0.z, xv0.w, xv1.x, xv1.y, xv1.z, xv1.w};
    const float mean = stats[row * 2], rstd = stats[row * 2 + 1];
    float uc[8], ua[8];
    load8_bf16(updc + row * DD + c0, uc);
    load8_bf16(upda + row * DD + c0, ua);
    const float mf = (mask[row] != 0) ? 1.f : 0.f;
    float y[8];
    float s = 0.f, ss = 0.f;
    #pragma unroll
    for (int e = 0; e < 8; e++) {
        int c = c0 + e;
        float xh = (xv[e] - mean) * rstd;
        float base = gb1[b * 512 + c] * (xh * fg[c] + fb[c]) + betab[b * 512 + c];
        float yv = base + gateb[b * 512 + c] * mf * (uc[e] + ua[e]);
        y[e] = yv; s += yv; ss += yv * yv;
    }
    for (int m = 1; m < 64; m <<= 1) { s += __shfl_xor(s, m, 64); ss += __shfl_xor(ss, m, 64); }
    float mean2 = s * (1.f / 512.f);
    float rstd2 = rsqrtf(ss * (1.f / 512.f) - mean2 * mean2 + 1e-5f);
    float o[8];
    #pragma unroll
    for (int e = 0; e < 8; e++) {
        int c = c0 + e;
        o[e] = (y[e] - mean2) * rstd2 * og[c] + ob[c];
    }
    *(float4*)(out + row * DD + c0)     = make_float4(o[0], o[1], o[2], o[3]);
    *(float4*)(out + row * DD + c0 + 4) = make_float4(o[4], o[5], o[6], o[7]);
}

extern "C" void kernel_launch(void* const* d_in, const int* in_sizes, int n_in,
                              void* d_out, int out_size, void* d_ws, size_t ws_size,
                              hipStream_t stream) {
    const float* x          = (const float*)d_in[0];
    const float* context    = (const float*)d_in[1];
    const int*   mask       = (const int*)d_in[2];
    const float* film_ln_g  = (const float*)d_in[3];
    const float* film_ln_b  = (const float*)d_in[4];
    const float* film_w     = (const float*)d_in[5];
    const float* film_b     = (const float*)d_in[6];
    const float* concat_w   = (const float*)d_in[7];
    const float* concat_b   = (const float*)d_in[8];
    const float* concat_ln_g= (const float*)d_in[9];
    const float* concat_ln_b= (const float*)d_in[10];
    const float* ctx_w1     = (const float*)d_in[11];
    const float* ctx_b1     = (const float*)d_in[12];
    const float* ctx_w2     = (const float*)d_in[13];
    const float* ctx_b2     = (const float*)d_in[14];
    const float* q_ln_g     = (const float*)d_in[15];
    const float* q_ln_b     = (const float*)d_in[16];
    const float* in_proj_w  = (const float*)d_in[17];
    const float* in_proj_b  = (const float*)d_in[18];
    const float* out_proj_w = (const float*)d_in[19];
    const float* out_proj_b = (const float*)d_in[20];
    const float* mix_w1     = (const float*)d_in[21];
    const float* mix_b1     = (const float*)d_in[22];
    const float* mix_w2     = (const float*)d_in[23];
    const float* mix_b2     = (const float*)d_in[24];
    const float* out_ln_g   = (const float*)d_in[25];
    const float* out_ln_b   = (const float*)d_in[26];
    const float* gate_w     = (const float*)d_in[27];
    const float* gate_b     = (const float*)d_in[28];
    float* out = (float*)d_out;

    // ---- workspace layout ----
    float* fw    = (float*)d_ws;
    float* gb1   = fw;                       // 8*512
    float* betab = gb1 + 8 * 512;
    float* gateb = betab + 8 * 512;
    float* kbuf  = gateb + 8 * 512;          // 8*2*512
    float* vbuf  = kbuf + 8 * 2 * 512;
    float* wqp   = vbuf + 8 * 2 * 512;       // 512*512
    float* bqp   = wqp + 512 * 512;          // 512
    float* stats = bqp + 512;                // N*2
    bf16* bufc = (bf16*)(stats + (size_t)N_TOK * 2);  // N*512
    bf16* bufq = bufc + (size_t)N_TOK * 512;          // N*512 (q, then attn_out)
    bf16* bufa = bufq + (size_t)N_TOK * 512;          // N*512 (a, then upd_a)
    bf16* bufh = bufa + (size_t)N_TOK * 512;          // N*1024

    ctx_kernel<<<8, 256, 0, stream>>>(context, film_w, film_b, gate_w, gate_b,
                                      ctx_w1, ctx_b1, ctx_w2, ctx_b2,
                                      in_proj_w, in_proj_b,
                                      gb1, betab, gateb, kbuf, vbuf);
    foldq_kernel<<<512, 256, 0, stream>>>(in_proj_w, in_proj_b, q_ln_g, q_ln_b, wqp, bqp);
    stats_kernel<<<N_TOK / 4, 256, 0, stream>>>(x, stats);

    gemm_kernel<0, true, 768><<<dim3(512, 8), 256, 0, stream>>>(
        x, context, nullptr, nullptr, concat_w, concat_b, bufc, 512);
    lnrows_kernel<<<N_TOK / 4, 256, 0, stream>>>(bufc, concat_ln_g, concat_ln_b);

    gemm_kernel<1, false, 512><<<dim3(512, 8), 256, 0, stream>>>(
        x, nullptr, stats, nullptr, wqp, bqp, bufq, 512);
    attn_kernel<<<N_TOK / 4, 256, 0, stream>>>(bufq, kbuf, vbuf, bufa);
    gemm_kernel<2, false, 512><<<dim3(512, 8), 256, 0, stream>>>(
        nullptr, nullptr, nullptr, bufa, out_proj_w, out_proj_b, bufq, 512);

    gemm_kernel<3, true, 2048><<<dim3(512, 16), 256, 0, stream>>>(
        x, nullptr, nullptr, bufq, mix_w1, mix_b1, bufh, 1024);
    gemm_kernel<2, false, 1024><<<dim3(512, 8), 256, 0, stream>>>(
        nullptr, nullptr, nullptr, bufh, mix_w2, mix_b2, bufa, 512);

    final_kernel<<<N_TOK / 4, 256, 0, stream>>>(x, stats, bufc, bufa,
                                                gb1, betab, gateb, mask,
                                                film_ln_g, film_ln_b,
                                                out_ln_g, out_ln_b, out);
    (void)in_sizes; (void)n_in; (void)out_size; (void)ws_size;
}

// Round 2
// 963.966 us; speedup vs baseline: 4.1270x; 4.1270x over previous
//
#include <hip/hip_runtime.h>
#include <hip/hip_bf16.h>

// HybridBridge MFMA version. B=8, L=4096, D=512, C=256, T=2, H=2, HD=256.
// N = 32768 rows. All GEMMs: bf16 MFMA 16x16x32, 128x128 tile, BK=64,
// global_load_lds(16B) staging (m97 structure).
//
// Workspace overlay (4 units of 32MB + weights ~6MB + small): ~140.6 MB
//   U2 bufc : upd_c (alive to end)
//   U3      : q -> ao -> upd_a
//   U1      : xbf -> a -> bufh[0:half]
//   U4      : bufh[half:]

#define N_TOK 32768

typedef unsigned short u16;
typedef __attribute__((ext_vector_type(8))) __bf16 bf16x8;
typedef __attribute__((ext_vector_type(4))) float f32x4;

__device__ __forceinline__ float bf2f(unsigned int h) { return __uint_as_float(h << 16); }
__device__ __forceinline__ u16 f2bf(float f) {
    unsigned int u = __float_as_uint(f);
    u += 0x7FFFu + ((u >> 16) & 1u);   // RNE
    return (u16)(u >> 16);
}
__device__ __forceinline__ void load8(const u16* p, float* v) {
    uint4 u = *(const uint4*)p;
    v[0] = bf2f(u.x & 0xffffu); v[1] = bf2f(u.x >> 16);
    v[2] = bf2f(u.y & 0xffffu); v[3] = bf2f(u.y >> 16);
    v[4] = bf2f(u.z & 0xffffu); v[5] = bf2f(u.z >> 16);
    v[6] = bf2f(u.w & 0xffffu); v[7] = bf2f(u.w >> 16);
}
__device__ __forceinline__ uint4 pack8(const float* v) {
    uint4 u;
    u.x = (unsigned)f2bf(v[0]) | ((unsigned)f2bf(v[1]) << 16);
    u.y = (unsigned)f2bf(v[2]) | ((unsigned)f2bf(v[3]) << 16);
    u.z = (unsigned)f2bf(v[4]) | ((unsigned)f2bf(v[5]) << 16);
    u.w = (unsigned)f2bf(v[6]) | ((unsigned)f2bf(v[7]) << 16);
    return u;
}
__device__ __forceinline__ void async16(const u16* g, u16* lds) {
    __builtin_amdgcn_global_load_lds(
        (const __attribute__((address_space(1))) unsigned int*)g,
        (__attribute__((address_space(3))) unsigned int*)lds, 16, 0, 0);
}

__device__ __forceinline__ float dotw(const float* __restrict__ w,
                                      const float* __restrict__ s, int n) {
    float acc = 0.f;
    for (int i = 0; i < n; i += 4) {
        float4 wv = *(const float4*)(w + i);
        acc += wv.x * s[i] + wv.y * s[i+1] + wv.z * s[i+2] + wv.w * s[i+3];
    }
    return acc;
}

// ==== per-batch context kernel ===========================================
__global__ void ctx_kernel(const float* __restrict__ context,
                           const float* __restrict__ film_w, const float* __restrict__ film_b,
                           const float* __restrict__ gate_w, const float* __restrict__ gate_b,
                           const float* __restrict__ ctx_w1, const float* __restrict__ ctx_b1,
                           const float* __restrict__ ctx_w2, const float* __restrict__ ctx_b2,
                           const float* __restrict__ in_proj_w, const float* __restrict__ in_proj_b,
                           float* __restrict__ gb1, float* __restrict__ betab,
                           float* __restrict__ gateb,
                           float* __restrict__ kbuf, float* __restrict__ vbuf,
                           u16* __restrict__ ctxbf) {
    const int b = blockIdx.x;
    const int tid = threadIdx.x;
    __shared__ float s_ctx[256];
    __shared__ float s_h[512];
    __shared__ float s_tok[1024];
    float cv = context[b * 256 + tid];
    s_ctx[tid] = cv;
    ctxbf[b * 256 + tid] = f2bf(cv);
    __syncthreads();
    #pragma unroll
    for (int rep = 0; rep < 2; rep++) {
        int j = tid + rep * 256;
        float g  = dotw(film_w + (size_t)j * 256, s_ctx, 256) + film_b[j];
        float be = dotw(film_w + (size_t)(512 + j) * 256, s_ctx, 256) + film_b[512 + j];
        float gt = dotw(gate_w + (size_t)j * 256, s_ctx, 256) + gate_b[j];
        float hv = dotw(ctx_w1 + (size_t)j * 256, s_ctx, 256) + ctx_b1[j];
        gb1[b * 512 + j]   = 1.0f + g;
        betab[b * 512 + j] = be;
        gateb[b * 512 + j] = 1.f / (1.f + expf(-gt));
        s_h[j] = 0.5f * hv * (1.0f + erff(hv * 0.70710678118654752f));
    }
    __syncthreads();
    #pragma unroll
    for (int rep = 0; rep < 4; rep++) {
        int j = tid + rep * 256;
        s_tok[j] = dotw(ctx_w2 + (size_t)j * 512, s_h, 512) + ctx_b2[j];
    }
    __syncthreads();
    #pragma unroll
    for (int t = 0; t < 2; t++) {
        #pragma unroll
        for (int rep = 0; rep < 2; rep++) {
            int j = tid + rep * 256;
            float kk = dotw(in_proj_w + (size_t)(512 + j) * 512,  s_tok + t * 512, 512) + in_proj_b[512 + j];
            float vv = dotw(in_proj_w + (size_t)(1024 + j) * 512, s_tok + t * 512, 512) + in_proj_b[1024 + j];
            kbuf[(b * 2 + t) * 512 + j] = kk;
            vbuf[(b * 2 + t) * 512 + j] = vv;
        }
    }
}

// ==== fold q-LN into wq: W'=wq*qg (bf16), s[n]=sum W', b'=bq+wq@qb ========
__global__ void foldq_kernel(const float* __restrict__ in_proj_w,
                             const float* __restrict__ in_proj_b,
                             const float* __restrict__ qg, const float* __restrict__ qb,
                             u16* __restrict__ wqbf, float* __restrict__ bqp,
                             float* __restrict__ sfac) {
    const int j = blockIdx.x;
    const int tid = threadIdx.x;
    __shared__ float red1[256], red2[256];
    float p1 = 0.f, p2 = 0.f;
    #pragma unroll
    for (int rep = 0; rep < 2; rep++) {
        int i = tid + rep * 256;
        float w = in_proj_w[(size_t)j * 512 + i];
        float wp = w * qg[i];
        wqbf[(size_t)j * 512 + i] = f2bf(wp);
        p1 += w * qb[i];
        p2 += wp;
    }
    red1[tid] = p1; red2[tid] = p2;
    __syncthreads();
    for (int s = 128; s > 0; s >>= 1) {
        if (tid < s) { red1[tid] += red1[tid + s]; red2[tid] += red2[tid + s]; }
        __syncthreads();
    }
    if (tid == 0) { bqp[j] = in_proj_b[j] + red1[0]; sfac[j] = red2[0]; }
}

// ==== generic fp32 -> bf16 weight convert ================================
__global__ void wconv_kernel(const float* __restrict__ src, u16* __restrict__ dst, int n8) {
    int i = blockIdx.x * blockDim.x + threadIdx.x;
    if (i >= n8) return;
    const float* s = src + (size_t)i * 8;
    float4 a = *(const float4*)s;
    float4 b = *(const float4*)(s + 4);
    float v[8] = {a.x, a.y, a.z, a.w, b.x, b.y, b.z, b.w};
    *(uint4*)(dst + (size_t)i * 8) = pack8(v);
}

// ==== build mix W': [Wa+Wc | Wb-Wc | Wd] 1024x1536 bf16 ==================
__global__ void wmix1_kernel(const float* __restrict__ W1, u16* __restrict__ dst) {
    int idx = blockIdx.x * 256 + threadIdx.x;      // < 196608
    int n = idx / 192;
    int k = (idx - n * 192) * 8;
    const float* base = W1 + (size_t)n * 2048;
    float v[8];
    if (k < 512) {
        #pragma unroll
        for (int e = 0; e < 8; e++) v[e] = base[k + e] + base[1024 + k + e];
    } else if (k < 1024) {
        #pragma unroll
        for (int e = 0; e < 8; e++) v[e] = base[k + e] - base[512 + k + e];
    } else {
        #pragma unroll
        for (int e = 0; e < 8; e++) v[e] = base[512 + k + e];
    }
    *(uint4*)(dst + (size_t)n * 1536 + k) = pack8(v);
}

// ==== per-row mean/rstd of x + x->bf16 ===================================
__global__ void stats_kernel(const float* __restrict__ x, float* __restrict__ stats,
                             u16* __restrict__ xbf) {
    const int wave = threadIdx.x >> 6, lane = threadIdx.x & 63;
    const size_t row = (size_t)blockIdx.x * 4 + wave;
    const float* xr = x + row * 512 + lane * 8;
    float4 a = *(const float4*)xr;
    float4 b = *(const float4*)(xr + 4);
    float v[8] = {a.x, a.y, a.z, a.w, b.x, b.y, b.z, b.w};
    float s = 0.f, ss = 0.f;
    #pragma unroll
    for (int e = 0; e < 8; e++) { s += v[e]; ss += v[e] * v[e]; }
    for (int m = 1; m < 64; m <<= 1) { s += __shfl_xor(s, m, 64); ss += __shfl_xor(ss, m, 64); }
    *(uint4*)(xbf + row * 512 + lane * 8) = pack8(v);
    float mean = s * (1.f / 512.f);
    float var  = ss * (1.f / 512.f) - mean * mean;
    if (lane == 0) { stats[row * 2] = mean; stats[row * 2 + 1] = rsqrtf(var + 1e-5f); }
}

// ==== MFMA GEMM: out = act(A @ W^T + bias) ===============================
// AMODE 0: A = A0 (bf16, ld=K)
// AMODE 1: A = [A0(xbf,512) | A1(ctxbf,256 per-batch broadcast)], K=768
// AMODE 2: A = [bf16(Af) | A1(ao) | bf16(Af)*A1], K=1536 (Af = fp32 x)
// EPI 0: v = acc + bias[c]           EPI 1: v = rstd*(acc - mean*sfac[c]) + bias[c]
template<int AMODE, int EPI, bool RELU>
__launch_bounds__(256)
__global__ void mfma_gemm(const u16* __restrict__ A0, const u16* __restrict__ A1,
                          const float* __restrict__ Af,
                          const u16* __restrict__ Wb, const float* __restrict__ bias,
                          const float* __restrict__ stats, const float* __restrict__ sfac,
                          u16* __restrict__ out, const int K, const int Dout) {
    __shared__ __align__(16) u16 As[128 * 64];
    __shared__ __align__(16) u16 Bs[128 * 64];
    const int tid = threadIdx.x;
    const int w = tid >> 6, l = tid & 63;
    const int wm = w >> 1, wn = w & 1;
    const size_t m0 = (size_t)blockIdx.x * 128;
    const int n0 = blockIdx.y * 128;
    const int rb = w * 8 + (l >> 3);      // staging row base 0..31
    const int kofs = (l & 7) * 8;
    const int bidx = (int)(m0 >> 12);
    const int quad = l >> 4, lc = l & 15;

    f32x4 acc[4][4];
    #pragma unroll
    for (int i = 0; i < 4; i++)
        #pragma unroll
        for (int j = 0; j < 4; j++) acc[i][j] = (f32x4){0.f, 0.f, 0.f, 0.f};

    for (int k0 = 0; k0 < K; k0 += 64) {
        __syncthreads();
        // ---- stage A tile 128x64 ----
        if constexpr (AMODE == 0) {
            #pragma unroll
            for (int r = 0; r < 4; r++) {
                const int row = r * 32 + rb;
                async16(A0 + (m0 + row) * (size_t)K + k0 + kofs, &As[r * 2048 + w * 512]);
            }
        } else if constexpr (AMODE == 1) {
            if (k0 < 512) {
                #pragma unroll
                for (int r = 0; r < 4; r++) {
                    const int row = r * 32 + rb;
                    async16(A0 + (m0 + row) * 512 + k0 + kofs, &As[r * 2048 + w * 512]);
                }
            } else {
                #pragma unroll
                for (int r = 0; r < 4; r++) {
                    async16(A1 + bidx * 256 + (k0 - 512) + kofs, &As[r * 2048 + w * 512]);
                }
            }
        } else {
            if (k0 < 512) {                 // bf16(x) on the fly
                #pragma unroll
                for (int r = 0; r < 4; r++) {
                    const int row = r * 32 + rb;
                    const float* g = Af + (m0 + row) * 512 + k0 + kofs;
                    float4 a = *(const float4*)g;
                    float4 b = *(const float4*)(g + 4);
                    float v[8] = {a.x, a.y, a.z, a.w, b.x, b.y, b.z, b.w};
                    *(uint4*)&As[r * 2048 + w * 512 + l * 8] = pack8(v);
                }
            } else if (k0 < 1024) {          // ao async
                #pragma unroll
                for (int r = 0; r < 4; r++) {
                    const int row = r * 32 + rb;
                    async16(A1 + (m0 + row) * 512 + (k0 - 512) + kofs, &As[r * 2048 + w * 512]);
                }
            } else {                          // x * ao on the fly
                #pragma unroll
                for (int r = 0; r < 4; r++) {
                    const int row = r * 32 + rb;
                    const float* g = Af + (m0 + row) * 512 + (k0 - 1024) + kofs;
                    float4 a = *(const float4*)g;
                    float4 b = *(const float4*)(g + 4);
                    float av[8];
                    load8(A1 + (m0 + row) * 512 + (k0 - 1024) + kofs, av);
                    float v[8] = {a.x * av[0], a.y * av[1], a.z * av[2], a.w * av[3],
                                  b.x * av[4], b.y * av[5], b.z * av[6], b.w * av[7]};
                    *(uint4*)&As[r * 2048 + w * 512 + l * 8] = pack8(v);
                }
            }
        }
        // ---- stage B tile 128x64 (W rows n0..n0+127) ----
        #pragma unroll
        for (int r = 0; r < 4; r++) {
            const int row = r * 32 + rb;
            async16(Wb + (size_t)(n0 + row) * K + k0 + kofs, &Bs[r * 2048 + w * 512]);
        }
        __syncthreads();
        // ---- compute: 2 x (K=32) chunks, 16 MFMA each per wave ----
        #pragma unroll
        for (int kk = 0; kk < 2; kk++) {
            bf16x8 af[4], bff[4];
            #pragma unroll
            for (int t = 0; t < 4; t++) {
                af[t]  = *(const bf16x8*)&As[(wm * 64 + t * 16 + lc) * 64 + kk * 32 + quad * 8];
                bff[t] = *(const bf16x8*)&Bs[(wn * 64 + t * 16 + lc) * 64 + kk * 32 + quad * 8];
            }
            #pragma unroll
            for (int i = 0; i < 4; i++)
                #pragma unroll
                for (int j = 0; j < 4; j++)
                    acc[i][j] = __builtin_amdgcn_mfma_f32_16x16x32_bf16(af[i], bff[j], acc[i][j], 0, 0, 0);
        }
    }

    // ---- epilogue: C/D layout col=lane&15, row=quad*4+reg ----
    #pragma unroll
    for (int i = 0; i < 4; i++) {
        #pragma unroll
        for (int reg = 0; reg < 4; reg++) {
            const size_t r = m0 + wm * 64 + i * 16 + quad * 4 + reg;
            float mean = 0.f, rstd = 0.f;
            if constexpr (EPI == 1) { mean = stats[r * 2]; rstd = stats[r * 2 + 1]; }
            #pragma unroll
            for (int j = 0; j < 4; j++) {
                const int c = n0 + wn * 64 + j * 16 + lc;
                float v = acc[i][j][reg];
                if constexpr (EPI == 1) v = rstd * (v - mean * sfac[c]) + bias[c];
                else                    v = v + bias[c];
                if (RELU) v = fmaxf(v, 0.f);
                out[r * (size_t)Dout + c] = f2bf(v);
            }
        }
    }
}

// ==== row LayerNorm on bf16 buffer (in place) ============================
__global__ void lnrows_kernel(u16* __restrict__ buf,
                              const float* __restrict__ g, const float* __restrict__ b) {
    const int wave = threadIdx.x >> 6, lane = threadIdx.x & 63;
    const size_t row = (size_t)blockIdx.x * 4 + wave;
    u16* p = buf + row * 512 + lane * 8;
    float v[8];
    load8(p, v);
    float s = 0.f, ss = 0.f;
    #pragma unroll
    for (int e = 0; e < 8; e++) { s += v[e]; ss += v[e] * v[e]; }
    for (int m = 1; m < 64; m <<= 1) { s += __shfl_xor(s, m, 64); ss += __shfl_xor(ss, m, 64); }
    float mean = s * (1.f / 512.f);
    float rstd = rsqrtf(ss * (1.f / 512.f) - mean * mean + 1e-5f);
    float o[8];
    #pragma unroll
    for (int e = 0; e < 8; e++) {
        int c = lane * 8 + e;
        o[e] = (v[e] - mean) * rstd * g[c] + b[c];
    }
    *(uint4*)p = pack8(o);
}

// ==== tiny attention: T=2, H=2, HD=256 ===================================
__global__ void attn_kernel(const u16* __restrict__ qbuf,
                            const float* __restrict__ kbuf, const float* __restrict__ vbuf,
                            u16* __restrict__ abuf) {
    const int wave = threadIdx.x >> 6, lane = threadIdx.x & 63;
    const size_t row = (size_t)blockIdx.x * 4 + wave;
    const int b = (int)(row >> 12);
    const int h = lane >> 5;
    const int off = h * 256 + (lane & 31) * 8;
    float q[8];
    load8(qbuf + row * 512 + off, q);
    const float* k0 = kbuf + (b * 2 + 0) * 512 + off;
    const float* k1 = kbuf + (b * 2 + 1) * 512 + off;
    float s0 = 0.f, s1 = 0.f;
    #pragma unroll
    for (int e = 0; e < 8; e++) { s0 += q[e] * k0[e]; s1 += q[e] * k1[e]; }
    for (int m = 1; m < 32; m <<= 1) { s0 += __shfl_xor(s0, m, 64); s1 += __shfl_xor(s1, m, 64); }
    s0 *= (1.f / 16.f); s1 *= (1.f / 16.f);
    float mx = fmaxf(s0, s1);
    float e0 = expf(s0 - mx), e1 = expf(s1 - mx);
    float inv = 1.f / (e0 + e1);
    float p0 = e0 * inv, p1 = e1 * inv;
    const float* v0 = vbuf + (b * 2 + 0) * 512 + off;
    const float* v1 = vbuf + (b * 2 + 1) * 512 + off;
    float a[8];
    #pragma unroll
    for (int e = 0; e < 8; e++) a[e] = p0 * v0[e] + p1 * v1[e];
    *(uint4*)(abuf + row * 512 + off) = pack8(a);
}

// ==== final: LN(base + gate*mask*(upd_c+upd_a)) ==========================
__global__ void final_kernel(const float* __restrict__ x, const float* __restrict__ stats,
                             const u16* __restrict__ updc, const u16* __restrict__ upda,
                             const float* __restrict__ gb1, const float* __restrict__ betab,
                             const float* __restrict__ gateb, const int* __restrict__ mask,
                             const float* __restrict__ fg, const float* __restrict__ fb,
                             const float* __restrict__ og, const float* __restrict__ ob,
                             float* __restrict__ out) {
    const int wave = threadIdx.x >> 6, lane = threadIdx.x & 63;
    const size_t row = (size_t)blockIdx.x * 4 + wave;
    const int b = (int)(row >> 12);
    const int c0 = lane * 8;
    float4 xv0 = *(const float4*)(x + row * 512 + c0);
    float4 xv1 = *(const float4*)(x + row * 512 + c0 + 4);
    float xv[8] = {xv0.x, xv0.y, xv0.z, xv0.w, xv1.x, xv1.y, xv1.z, xv1.w};
    const float mean = stats[row * 2], rstd = stats[row * 2 + 1];
    float uc[8], ua[8];
    load8(updc + row * 512 + c0, uc);
    load8(upda + row * 512 + c0, ua);
    const float mf = (mask[row] != 0) ? 1.f : 0.f;
    float y[8];
    float s = 0.f, ss = 0.f;
    #pragma unroll
    for (int e = 0; e < 8; e++) {
        int c = c0 + e;
        float xh = (xv[e] - mean) * rstd;
        float base = gb1[b * 512 + c] * (xh * fg[c] + fb[c]) + betab[b * 512 + c];
        float yv = base + gateb[b * 512 + c] * mf * (uc[e] + ua[e]);
        y[e] = yv; s += yv; ss += yv * yv;
    }
    for (int m = 1; m < 64; m <<= 1) { s += __shfl_xor(s, m, 64); ss += __shfl_xor(ss, m, 64); }
    float mean2 = s * (1.f / 512.f);
    float rstd2 = rsqrtf(ss * (1.f / 512.f) - mean2 * mean2 + 1e-5f);
    float o[8];
    #pragma unroll
    for (int e = 0; e < 8; e++) {
        int c = c0 + e;
        o[e] = (y[e] - mean2) * rstd2 * og[c] + ob[c];
    }
    *(float4*)(out + row * 512 + c0)     = make_float4(o[0], o[1], o[2], o[3]);
    *(float4*)(out + row * 512 + c0 + 4) = make_float4(o[4], o[5], o[6], o[7]);
}

extern "C" void kernel_launch(void* const* d_in, const int* in_sizes, int n_in,
                              void* d_out, int out_size, void* d_ws, size_t ws_size,
                              hipStream_t stream) {
    const float* x          = (const float*)d_in[0];
    const float* context    = (const float*)d_in[1];
    const int*   mask       = (const int*)d_in[2];
    const float* film_ln_g  = (const float*)d_in[3];
    const float* film_ln_b  = (const float*)d_in[4];
    const float* film_w     = (const float*)d_in[5];
    const float* film_b     = (const float*)d_in[6];
    const float* concat_w   = (const float*)d_in[7];
    const float* concat_b   = (const float*)d_in[8];
    const float* concat_ln_g= (const float*)d_in[9];
    const float* concat_ln_b= (const float*)d_in[10];
    const float* ctx_w1     = (const float*)d_in[11];
    const float* ctx_b1     = (const float*)d_in[12];
    const float* ctx_w2     = (const float*)d_in[13];
    const float* ctx_b2     = (const float*)d_in[14];
    const float* q_ln_g     = (const float*)d_in[15];
    const float* q_ln_b     = (const float*)d_in[16];
    const float* in_proj_w  = (const float*)d_in[17];
    const float* in_proj_b  = (const float*)d_in[18];
    const float* out_proj_w = (const float*)d_in[19];
    const float* out_proj_b = (const float*)d_in[20];
    const float* mix_w1     = (const float*)d_in[21];
    const float* mix_b1     = (const float*)d_in[22];
    const float* mix_w2     = (const float*)d_in[23];
    const float* mix_b2     = (const float*)d_in[24];
    const float* out_ln_g   = (const float*)d_in[25];
    const float* out_ln_b   = (const float*)d_in[26];
    const float* gate_w     = (const float*)d_in[27];
    const float* gate_b     = (const float*)d_in[28];
    float* out = (float*)d_out;

    // ---- workspace layout (~140.6 MB) ----
    float* gb1   = (float*)d_ws;             // 4096
    float* betab = gb1 + 4096;
    float* gateb = betab + 4096;
    float* kbuf  = gateb + 4096;             // 8192
    float* vbuf  = kbuf + 8192;
    float* bqp   = vbuf + 8192;              // 512
    float* sfac  = bqp + 512;                // 512
    float* stats = sfac + 512;               // 65536
    u16* ctxbf = (u16*)(stats + 65536);      // 2048
    u16* cwbf  = ctxbf + 2048;               // 393216
    u16* wqbf  = cwbf + 393216;              // 262144
    u16* owbf  = wqbf + 262144;              // 262144
    u16* m1bf  = owbf + 262144;              // 1572864
    u16* m2bf  = m1bf + 1572864;             // 524288
    u16* bufc  = m2bf + 524288;              // U2: 16777216  upd_c
    u16* q_ao  = bufc + 16777216;            // U3: q -> ao -> upd_a
    u16* xbf_a = q_ao + 16777216;            // U1: xbf -> a -> bufh lower
    u16* bufh  = xbf_a;                      // spans U1+U4 (33554432 elems)

    ctx_kernel<<<8, 256, 0, stream>>>(context, film_w, film_b, gate_w, gate_b,
                                      ctx_w1, ctx_b1, ctx_w2, ctx_b2,
                                      in_proj_w, in_proj_b,
                                      gb1, betab, gateb, kbuf, vbuf, ctxbf);
    foldq_kernel<<<512, 256, 0, stream>>>(in_proj_w, in_proj_b, q_ln_g, q_ln_b,
                                          wqbf, bqp, sfac);
    wconv_kernel<<<192, 256, 0, stream>>>(concat_w, cwbf, 49152);
    wconv_kernel<<<128, 256, 0, stream>>>(out_proj_w, owbf, 32768);
    wconv_kernel<<<256, 256, 0, stream>>>(mix_w2, m2bf, 65536);
    wmix1_kernel<<<768, 256, 0, stream>>>(mix_w1, m1bf);
    stats_kernel<<<N_TOK / 4, 256, 0, stream>>>(x, stats, xbf_a);

    // concat: relu([x|ctx] @ concat_w^T + b) -> bufc, then LN
    mfma_gemm<1, 0, true><<<dim3(256, 4), 256, 0, stream>>>(
        xbf_a, ctxbf, nullptr, cwbf, concat_b, nullptr, nullptr, bufc, 768, 512);
    lnrows_kernel<<<N_TOK / 4, 256, 0, stream>>>(bufc, concat_ln_g, concat_ln_b);

    // q = rstd*(x @ W'^T - mean*s) + b' -> q_ao
    mfma_gemm<0, 1, false><<<dim3(256, 4), 256, 0, stream>>>(
        xbf_a, nullptr, nullptr, wqbf, bqp, stats, sfac, q_ao, 512, 512);
    attn_kernel<<<N_TOK / 4, 256, 0, stream>>>(q_ao, kbuf, vbuf, xbf_a);  // a -> U1
    // ao = a @ out_proj^T + b -> q_ao (q dead)
    mfma_gemm<0, 0, false><<<dim3(256, 4), 256, 0, stream>>>(
        xbf_a, nullptr, nullptr, owbf, out_proj_b, nullptr, nullptr, q_ao, 512, 512);

    // h = relu([x|ao|x*ao] @ W1'^T + b) -> bufh (U1+U4; a dead)
    mfma_gemm<2, 0, true><<<dim3(256, 8), 256, 0, stream>>>(
        nullptr, q_ao, x, m1bf, mix_b1, nullptr, nullptr, bufh, 1536, 1024);
    // upd_a = h @ mix_w2^T + b -> q_ao (ao dead)
    mfma_gemm<0, 0, false><<<dim3(256, 4), 256, 0, stream>>>(
        bufh, nullptr, nullptr, m2bf, mix_b2, nullptr, nullptr, q_ao, 1024, 512);

    final_kernel<<<N_TOK / 4, 256, 0, stream>>>(x, stats, bufc, q_ao,
                                                gb1, betab, gateb, mask,
                                                film_ln_g, film_ln_b,
                                                out_ln_g, out_ln_b, out);
    (void)in_sizes; (void)n_in; (void)out_size; (void)ws_size;
}

// Round 3
// 631.289 us; speedup vs baseline: 6.3019x; 1.5270x over previous
//
#include <hip/hip_runtime.h>
#include <hip/hip_bf16.h>

// HybridBridge MFMA version, round 3: parallel context path.
// B=8, L=4096, D=512, C=256, T=2, H=2, HD=256. N = 32768 rows.
// GEMMs: bf16 MFMA 16x16x32, 128x128 tile, BK=64, global_load_lds(16B).

#define N_TOK 32768

typedef unsigned short u16;
typedef __attribute__((ext_vector_type(8))) __bf16 bf16x8;
typedef __attribute__((ext_vector_type(4))) float f32x4;

__device__ __forceinline__ float bf2f(unsigned int h) { return __uint_as_float(h << 16); }
__device__ __forceinline__ u16 f2bf(float f) {
    unsigned int u = __float_as_uint(f);
    u += 0x7FFFu + ((u >> 16) & 1u);   // RNE
    return (u16)(u >> 16);
}
__device__ __forceinline__ void load8(const u16* p, float* v) {
    uint4 u = *(const uint4*)p;
    v[0] = bf2f(u.x & 0xffffu); v[1] = bf2f(u.x >> 16);
    v[2] = bf2f(u.y & 0xffffu); v[3] = bf2f(u.y >> 16);
    v[4] = bf2f(u.z & 0xffffu); v[5] = bf2f(u.z >> 16);
    v[6] = bf2f(u.w & 0xffffu); v[7] = bf2f(u.w >> 16);
}
__device__ __forceinline__ uint4 pack8(const float* v) {
    uint4 u;
    u.x = (unsigned)f2bf(v[0]) | ((unsigned)f2bf(v[1]) << 16);
    u.y = (unsigned)f2bf(v[2]) | ((unsigned)f2bf(v[3]) << 16);
    u.z = (unsigned)f2bf(v[4]) | ((unsigned)f2bf(v[5]) << 16);
    u.w = (unsigned)f2bf(v[6]) | ((unsigned)f2bf(v[7]) << 16);
    return u;
}
__device__ __forceinline__ void async16(const u16* g, u16* lds) {
    __builtin_amdgcn_global_load_lds(
        (const __attribute__((address_space(1))) unsigned int*)g,
        (__attribute__((address_space(3))) unsigned int*)lds, 16, 0, 0);
}

// ==== context stage A: film gamma/beta, gate, gelu(h). wave-per-output ===
// 16384 waves: b(8) x [gamma(512) | beta(512) | gate(512) | h(512)]
__global__ void ctx_stage_a(const float* __restrict__ context,
                            const float* __restrict__ film_w, const float* __restrict__ film_b,
                            const float* __restrict__ gate_w, const float* __restrict__ gate_b,
                            const float* __restrict__ ctx_w1, const float* __restrict__ ctx_b1,
                            float* __restrict__ gb1, float* __restrict__ betab,
                            float* __restrict__ gateb, float* __restrict__ hbuf,
                            u16* __restrict__ ctxbf) {
    if (blockIdx.x == 0) {  // also convert context -> bf16 (2048 elems)
        for (int i = threadIdx.x; i < 2048; i += 256)
            ctxbf[i] = f2bf(context[i]);
    }
    const int wave = threadIdx.x >> 6, lane = threadIdx.x & 63;
    const int widx = blockIdx.x * 4 + wave;       // 0..16383
    const int b   = widx >> 11;
    const int j2  = widx & 2047;
    const int cat = j2 >> 9;
    const int j   = j2 & 511;
    const float* wrow;
    if      (cat == 0) wrow = film_w + (size_t)j * 256;
    else if (cat == 1) wrow = film_w + (size_t)(512 + j) * 256;
    else if (cat == 2) wrow = gate_w + (size_t)j * 256;
    else               wrow = ctx_w1 + (size_t)j * 256;
    float4 wv = *(const float4*)(wrow + lane * 4);
    float4 cv = *(const float4*)(context + b * 256 + lane * 4);
    float s = wv.x * cv.x + wv.y * cv.y + wv.z * cv.z + wv.w * cv.w;
    for (int m = 1; m < 64; m <<= 1) s += __shfl_xor(s, m, 64);
    if (lane == 0) {
        if      (cat == 0) gb1[b * 512 + j]   = 1.0f + s + film_b[j];
        else if (cat == 1) betab[b * 512 + j] = s + film_b[512 + j];
        else if (cat == 2) gateb[b * 512 + j] = 1.f / (1.f + expf(-(s + gate_b[j])));
        else {
            float hv = s + ctx_b1[j];
            hbuf[b * 512 + j] = 0.5f * hv * (1.0f + erff(hv * 0.70710678118654752f));
        }
    }
}

// ==== context stage B: ctx_tok = h @ ctx_w2^T + b2. 8192 waves ===========
__global__ void ctx_stage_b(const float* __restrict__ hbuf,
                            const float* __restrict__ ctx_w2, const float* __restrict__ ctx_b2,
                            float* __restrict__ tokbuf) {
    const int wave = threadIdx.x >> 6, lane = threadIdx.x & 63;
    const int widx = blockIdx.x * 4 + wave;       // 0..8191
    const int b = widx >> 10;
    const int j = widx & 1023;
    const float* wrow = ctx_w2 + (size_t)j * 512 + lane * 8;
    const float* hr   = hbuf + b * 512 + lane * 8;
    float4 w0 = *(const float4*)wrow, w1 = *(const float4*)(wrow + 4);
    float4 h0 = *(const float4*)hr,   h1 = *(const float4*)(hr + 4);
    float s = w0.x*h0.x + w0.y*h0.y + w0.z*h0.z + w0.w*h0.w
            + w1.x*h1.x + w1.y*h1.y + w1.z*h1.z + w1.w*h1.w;
    for (int m = 1; m < 64; m <<= 1) s += __shfl_xor(s, m, 64);
    if (lane == 0) tokbuf[b * 1024 + j] = s + ctx_b2[j];
}

// ==== context stage C: k,v = tok @ wk/wv^T + b. 16384 waves ==============
__global__ void ctx_stage_c(const float* __restrict__ tokbuf,
                            const float* __restrict__ in_proj_w, const float* __restrict__ in_proj_b,
                            float* __restrict__ kbuf, float* __restrict__ vbuf) {
    const int wave = threadIdx.x >> 6, lane = threadIdx.x & 63;
    const int widx = blockIdx.x * 4 + wave;       // 0..16383
    const int b  = widx >> 11;
    const int r  = widx & 2047;
    const int t  = r >> 10;
    const int kv = (r >> 9) & 1;
    const int j  = r & 511;
    const float* wrow = in_proj_w + (size_t)(512 + kv * 512 + j) * 512 + lane * 8;
    const float* tk   = tokbuf + (b * 2 + t) * 512 + lane * 8;
    float4 w0 = *(const float4*)wrow, w1 = *(const float4*)(wrow + 4);
    float4 t0 = *(const float4*)tk,   t1 = *(const float4*)(tk + 4);
    float s = w0.x*t0.x + w0.y*t0.y + w0.z*t0.z + w0.w*t0.w
            + w1.x*t1.x + w1.y*t1.y + w1.z*t1.z + w1.w*t1.w;
    for (int m = 1; m < 64; m <<= 1) s += __shfl_xor(s, m, 64);
    if (lane == 0) {
        float v = s + in_proj_b[512 + kv * 512 + j];
        if (kv == 0) kbuf[(b * 2 + t) * 512 + j] = v;
        else         vbuf[(b * 2 + t) * 512 + j] = v;
    }
}

// ==== fold q-LN into wq: W'=wq*qg (bf16), s[n]=sum W', b'=bq+wq@qb ========
__global__ void foldq_kernel(const float* __restrict__ in_proj_w,
                             const float* __restrict__ in_proj_b,
                             const float* __restrict__ qg, const float* __restrict__ qb,
                             u16* __restrict__ wqbf, float* __restrict__ bqp,
                             float* __restrict__ sfac) {
    const int wave = threadIdx.x >> 6, lane = threadIdx.x & 63;
    const int j = blockIdx.x * 4 + wave;          // 0..511
    const int i = lane * 8;
    float4 w0 = *(const float4*)(in_proj_w + (size_t)j * 512 + i);
    float4 w1 = *(const float4*)(in_proj_w + (size_t)j * 512 + i + 4);
    float4 g0 = *(const float4*)(qg + i);
    float4 g1 = *(const float4*)(qg + i + 4);
    float4 b0 = *(const float4*)(qb + i);
    float4 b1 = *(const float4*)(qb + i + 4);
    float wp[8] = {w0.x*g0.x, w0.y*g0.y, w0.z*g0.z, w0.w*g0.w,
                   w1.x*g1.x, w1.y*g1.y, w1.z*g1.z, w1.w*g1.w};
    float p1 = w0.x*b0.x + w0.y*b0.y + w0.z*b0.z + w0.w*b0.w
             + w1.x*b1.x + w1.y*b1.y + w1.z*b1.z + w1.w*b1.w;
    float p2 = wp[0]+wp[1]+wp[2]+wp[3]+wp[4]+wp[5]+wp[6]+wp[7];
    *(uint4*)(wqbf + (size_t)j * 512 + i) = pack8(wp);
    for (int m = 1; m < 64; m <<= 1) { p1 += __shfl_xor(p1, m, 64); p2 += __shfl_xor(p2, m, 64); }
    if (lane == 0) { bqp[j] = in_proj_b[j] + p1; sfac[j] = p2; }
}

// ==== generic fp32 -> bf16 weight convert ================================
__global__ void wconv_kernel(const float* __restrict__ src, u16* __restrict__ dst, int n8) {
    int i = blockIdx.x * blockDim.x + threadIdx.x;
    if (i >= n8) return;
    const float* s = src + (size_t)i * 8;
    float4 a = *(const float4*)s;
    float4 b = *(const float4*)(s + 4);
    float v[8] = {a.x, a.y, a.z, a.w, b.x, b.y, b.z, b.w};
    *(uint4*)(dst + (size_t)i * 8) = pack8(v);
}

// ==== build mix W': [Wa+Wc | Wb-Wc | Wd] 1024x1536 bf16 ==================
__global__ void wmix1_kernel(const float* __restrict__ W1, u16* __restrict__ dst) {
    int idx = blockIdx.x * 256 + threadIdx.x;      // < 196608
    int n = idx / 192;
    int k = (idx - n * 192) * 8;
    const float* base = W1 + (size_t)n * 2048;
    float v[8];
    if (k < 512) {
        #pragma unroll
        for (int e = 0; e < 8; e++) v[e] = base[k + e] + base[1024 + k + e];
    } else if (k < 1024) {
        #pragma unroll
        for (int e = 0; e < 8; e++) v[e] = base[k + e] - base[512 + k + e];
    } else {
        #pragma unroll
        for (int e = 0; e < 8; e++) v[e] = base[512 + k + e];
    }
    *(uint4*)(dst + (size_t)n * 1536 + k) = pack8(v);
}

// ==== per-row mean/rstd of x + x->bf16 ===================================
__global__ void stats_kernel(const float* __restrict__ x, float* __restrict__ stats,
                             u16* __restrict__ xbf) {
    const int wave = threadIdx.x >> 6, lane = threadIdx.x & 63;
    const size_t row = (size_t)blockIdx.x * 4 + wave;
    const float* xr = x + row * 512 + lane * 8;
    float4 a = *(const float4*)xr;
    float4 b = *(const float4*)(xr + 4);
    float v[8] = {a.x, a.y, a.z, a.w, b.x, b.y, b.z, b.w};
    float s = 0.f, ss = 0.f;
    #pragma unroll
    for (int e = 0; e < 8; e++) { s += v[e]; ss += v[e] * v[e]; }
    for (int m = 1; m < 64; m <<= 1) { s += __shfl_xor(s, m, 64); ss += __shfl_xor(ss, m, 64); }
    *(uint4*)(xbf + row * 512 + lane * 8) = pack8(v);
    float mean = s * (1.f / 512.f);
    float var  = ss * (1.f / 512.f) - mean * mean;
    if (lane == 0) { stats[row * 2] = mean; stats[row * 2 + 1] = rsqrtf(var + 1e-5f); }
}

// ==== MFMA GEMM: out = act(A @ W^T + bias) ===============================
// AMODE 0: A = A0 (bf16, ld=K)
// AMODE 1: A = [A0(xbf,512) | A1(ctxbf,256 per-batch broadcast)], K=768
// AMODE 2: A = [bf16(Af) | A1(ao) | bf16(Af)*A1], K=1536 (Af = fp32 x)
// EPI 0: v = acc + bias[c]           EPI 1: v = rstd*(acc - mean*sfac[c]) + bias[c]
template<int AMODE, int EPI, bool RELU>
__launch_bounds__(256)
__global__ void mfma_gemm(const u16* __restrict__ A0, const u16* __restrict__ A1,
                          const float* __restrict__ Af,
                          const u16* __restrict__ Wb, const float* __restrict__ bias,
                          const float* __restrict__ stats, const float* __restrict__ sfac,
                          u16* __restrict__ out, const int K, const int Dout) {
    __shared__ __align__(16) u16 As[128 * 64];
    __shared__ __align__(16) u16 Bs[128 * 64];
    const int tid = threadIdx.x;
    const int w = tid >> 6, l = tid & 63;
    const int wm = w >> 1, wn = w & 1;
    const size_t m0 = (size_t)blockIdx.x * 128;
    const int n0 = blockIdx.y * 128;
    const int rb = w * 8 + (l >> 3);      // staging row base 0..31
    const int kofs = (l & 7) * 8;
    const int bidx = (int)(m0 >> 12);
    const int quad = l >> 4, lc = l & 15;

    f32x4 acc[4][4];
    #pragma unroll
    for (int i = 0; i < 4; i++)
        #pragma unroll
        for (int j = 0; j < 4; j++) acc[i][j] = (f32x4){0.f, 0.f, 0.f, 0.f};

    for (int k0 = 0; k0 < K; k0 += 64) {
        __syncthreads();
        // ---- stage A tile 128x64 ----
        if constexpr (AMODE == 0) {
            #pragma unroll
            for (int r = 0; r < 4; r++) {
                const int row = r * 32 + rb;
                async16(A0 + (m0 + row) * (size_t)K + k0 + kofs, &As[r * 2048 + w * 512]);
            }
        } else if constexpr (AMODE == 1) {
            if (k0 < 512) {
                #pragma unroll
                for (int r = 0; r < 4; r++) {
                    const int row = r * 32 + rb;
                    async16(A0 + (m0 + row) * 512 + k0 + kofs, &As[r * 2048 + w * 512]);
                }
            } else {
                #pragma unroll
                for (int r = 0; r < 4; r++) {
                    async16(A1 + bidx * 256 + (k0 - 512) + kofs, &As[r * 2048 + w * 512]);
                }
            }
        } else {
            if (k0 < 512) {                 // bf16(x) on the fly
                #pragma unroll
                for (int r = 0; r < 4; r++) {
                    const int row = r * 32 + rb;
                    const float* g = Af + (m0 + row) * 512 + k0 + kofs;
                    float4 a = *(const float4*)g;
                    float4 b = *(const float4*)(g + 4);
                    float v[8] = {a.x, a.y, a.z, a.w, b.x, b.y, b.z, b.w};
                    *(uint4*)&As[r * 2048 + w * 512 + l * 8] = pack8(v);
                }
            } else if (k0 < 1024) {          // ao async
                #pragma unroll
                for (int r = 0; r < 4; r++) {
                    const int row = r * 32 + rb;
                    async16(A1 + (m0 + row) * 512 + (k0 - 512) + kofs, &As[r * 2048 + w * 512]);
                }
            } else {                          // x * ao on the fly
                #pragma unroll
                for (int r = 0; r < 4; r++) {
                    const int row = r * 32 + rb;
                    const float* g = Af + (m0 + row) * 512 + (k0 - 1024) + kofs;
                    float4 a = *(const float4*)g;
                    float4 b = *(const float4*)(g + 4);
                    float av[8];
                    load8(A1 + (m0 + row) * 512 + (k0 - 1024) + kofs, av);
                    float v[8] = {a.x * av[0], a.y * av[1], a.z * av[2], a.w * av[3],
                                  b.x * av[4], b.y * av[5], b.z * av[6], b.w * av[7]};
                    *(uint4*)&As[r * 2048 + w * 512 + l * 8] = pack8(v);
                }
            }
        }
        // ---- stage B tile 128x64 (W rows n0..n0+127) ----
        #pragma unroll
        for (int r = 0; r < 4; r++) {
            const int row = r * 32 + rb;
            async16(Wb + (size_t)(n0 + row) * K + k0 + kofs, &Bs[r * 2048 + w * 512]);
        }
        __syncthreads();
        // ---- compute: 2 x (K=32) chunks, 16 MFMA each per wave ----
        #pragma unroll
        for (int kk = 0; kk < 2; kk++) {
            bf16x8 af[4], bff[4];
            #pragma unroll
            for (int t = 0; t < 4; t++) {
                af[t]  = *(const bf16x8*)&As[(wm * 64 + t * 16 + lc) * 64 + kk * 32 + quad * 8];
                bff[t] = *(const bf16x8*)&Bs[(wn * 64 + t * 16 + lc) * 64 + kk * 32 + quad * 8];
            }
            #pragma unroll
            for (int i = 0; i < 4; i++)
                #pragma unroll
                for (int j = 0; j < 4; j++)
                    acc[i][j] = __builtin_amdgcn_mfma_f32_16x16x32_bf16(af[i], bff[j], acc[i][j], 0, 0, 0);
        }
    }

    // ---- epilogue: C/D layout col=lane&15, row=quad*4+reg ----
    #pragma unroll
    for (int i = 0; i < 4; i++) {
        #pragma unroll
        for (int reg = 0; reg < 4; reg++) {
            const size_t r = m0 + wm * 64 + i * 16 + quad * 4 + reg;
            float mean = 0.f, rstd = 0.f;
            if constexpr (EPI == 1) { mean = stats[r * 2]; rstd = stats[r * 2 + 1]; }
            #pragma unroll
            for (int j = 0; j < 4; j++) {
                const int c = n0 + wn * 64 + j * 16 + lc;
                float v = acc[i][j][reg];
                if constexpr (EPI == 1) v = rstd * (v - mean * sfac[c]) + bias[c];
                else                    v = v + bias[c];
                if (RELU) v = fmaxf(v, 0.f);
                out[r * (size_t)Dout + c] = f2bf(v);
            }
        }
    }
}

// ==== row LayerNorm on bf16 buffer (in place) ============================
__global__ void lnrows_kernel(u16* __restrict__ buf,
                              const float* __restrict__ g, const float* __restrict__ b) {
    const int wave = threadIdx.x >> 6, lane = threadIdx.x & 63;
    const size_t row = (size_t)blockIdx.x * 4 + wave;
    u16* p = buf + row * 512 + lane * 8;
    float v[8];
    load8(p, v);
    float s = 0.f, ss = 0.f;
    #pragma unroll
    for (int e = 0; e < 8; e++) { s += v[e]; ss += v[e] * v[e]; }
    for (int m = 1; m < 64; m <<= 1) { s += __shfl_xor(s, m, 64); ss += __shfl_xor(ss, m, 64); }
    float mean = s * (1.f / 512.f);
    float rstd = rsqrtf(ss * (1.f / 512.f) - mean * mean + 1e-5f);
    float o[8];
    #pragma unroll
    for (int e = 0; e < 8; e++) {
        int c = lane * 8 + e;
        o[e] = (v[e] - mean) * rstd * g[c] + b[c];
    }
    *(uint4*)p = pack8(o);
}

// ==== tiny attention: T=2, H=2, HD=256 ===================================
__global__ void attn_kernel(const u16* __restrict__ qbuf,
                            const float* __restrict__ kbuf, const float* __restrict__ vbuf,
                            u16* __restrict__ abuf) {
    const int wave = threadIdx.x >> 6, lane = threadIdx.x & 63;
    const size_t row = (size_t)blockIdx.x * 4 + wave;
    const int b = (int)(row >> 12);
    const int h = lane >> 5;
    const int off = h * 256 + (lane & 31) * 8;
    float q[8];
    load8(qbuf + row * 512 + off, q);
    const float* k0 = kbuf + (b * 2 + 0) * 512 + off;
    const float* k1 = kbuf + (b * 2 + 1) * 512 + off;
    float s0 = 0.f, s1 = 0.f;
    #pragma unroll
    for (int e = 0; e < 8; e++) { s0 += q[e] * k0[e]; s1 += q[e] * k1[e]; }
    for (int m = 1; m < 32; m <<= 1) { s0 += __shfl_xor(s0, m, 64); s1 += __shfl_xor(s1, m, 64); }
    s0 *= (1.f / 16.f); s1 *= (1.f / 16.f);
    float mx = fmaxf(s0, s1);
    float e0 = expf(s0 - mx), e1 = expf(s1 - mx);
    float inv = 1.f / (e0 + e1);
    float p0 = e0 * inv, p1 = e1 * inv;
    const float* v0 = vbuf + (b * 2 + 0) * 512 + off;
    const float* v1 = vbuf + (b * 2 + 1) * 512 + off;
    float a[8];
    #pragma unroll
    for (int e = 0; e < 8; e++) a[e] = p0 * v0[e] + p1 * v1[e];
    *(uint4*)(abuf + row * 512 + off) = pack8(a);
}

// ==== final: LN(base + gate*mask*(upd_c+upd_a)) ==========================
__global__ void final_kernel(const float* __restrict__ x, const float* __restrict__ stats,
                             const u16* __restrict__ updc, const u16* __restrict__ upda,
                             const float* __restrict__ gb1, const float* __restrict__ betab,
                             const float* __restrict__ gateb, const int* __restrict__ mask,
                             const float* __restrict__ fg, const float* __restrict__ fb,
                             const float* __restrict__ og, const float* __restrict__ ob,
                             float* __restrict__ out) {
    const int wave = threadIdx.x >> 6, lane = threadIdx.x & 63;
    const size_t row = (size_t)blockIdx.x * 4 + wave;
    const int b = (int)(row >> 12);
    const int c0 = lane * 8;
    float4 xv0 = *(const float4*)(x + row * 512 + c0);
    float4 xv1 = *(const float4*)(x + row * 512 + c0 + 4);
    float xv[8] = {xv0.x, xv0.y, xv0.z, xv0.w, xv1.x, xv1.y, xv1.z, xv1.w};
    const float mean = stats[row * 2], rstd = stats[row * 2 + 1];
    float uc[8], ua[8];
    load8(updc + row * 512 + c0, uc);
    load8(upda + row * 512 + c0, ua);
    const float mf = (mask[row] != 0) ? 1.f : 0.f;
    float y[8];
    float s = 0.f, ss = 0.f;
    #pragma unroll
    for (int e = 0; e < 8; e++) {
        int c = c0 + e;
        float xh = (xv[e] - mean) * rstd;
        float base = gb1[b * 512 + c] * (xh * fg[c] + fb[c]) + betab[b * 512 + c];
        float yv = base + gateb[b * 512 + c] * mf * (uc[e] + ua[e]);
        y[e] = yv; s += yv; ss += yv * yv;
    }
    for (int m = 1; m < 64; m <<= 1) { s += __shfl_xor(s, m, 64); ss += __shfl_xor(ss, m, 64); }
    float mean2 = s * (1.f / 512.f);
    float rstd2 = rsqrtf(ss * (1.f / 512.f) - mean2 * mean2 + 1e-5f);
    float o[8];
    #pragma unroll
    for (int e = 0; e < 8; e++) {
        int c = c0 + e;
        o[e] = (y[e] - mean2) * rstd2 * og[c] + ob[c];
    }
    *(float4*)(out + row * 512 + c0)     = make_float4(o[0], o[1], o[2], o[3]);
    *(float4*)(out + row * 512 + c0 + 4) = make_float4(o[4], o[5], o[6], o[7]);
}

extern "C" void kernel_launch(void* const* d_in, const int* in_sizes, int n_in,
                              void* d_out, int out_size, void* d_ws, size_t ws_size,
                              hipStream_t stream) {
    const float* x          = (const float*)d_in[0];
    const float* context    = (const float*)d_in[1];
    const int*   mask       = (const int*)d_in[2];
    const float* film_ln_g  = (const float*)d_in[3];
    const float* film_ln_b  = (const float*)d_in[4];
    const float* film_w     = (const float*)d_in[5];
    const float* film_b     = (const float*)d_in[6];
    const float* concat_w   = (const float*)d_in[7];
    const float* concat_b   = (const float*)d_in[8];
    const float* concat_ln_g= (const float*)d_in[9];
    const float* concat_ln_b= (const float*)d_in[10];
    const float* ctx_w1     = (const float*)d_in[11];
    const float* ctx_b1     = (const float*)d_in[12];
    const float* ctx_w2     = (const float*)d_in[13];
    const float* ctx_b2     = (const float*)d_in[14];
    const float* q_ln_g     = (const float*)d_in[15];
    const float* q_ln_b     = (const float*)d_in[16];
    const float* in_proj_w  = (const float*)d_in[17];
    const float* in_proj_b  = (const float*)d_in[18];
    const float* out_proj_w = (const float*)d_in[19];
    const float* out_proj_b = (const float*)d_in[20];
    const float* mix_w1     = (const float*)d_in[21];
    const float* mix_b1     = (const float*)d_in[22];
    const float* mix_w2     = (const float*)d_in[23];
    const float* mix_b2     = (const float*)d_in[24];
    const float* out_ln_g   = (const float*)d_in[25];
    const float* out_ln_b   = (const float*)d_in[26];
    const float* gate_w     = (const float*)d_in[27];
    const float* gate_b     = (const float*)d_in[28];
    float* out = (float*)d_out;

    // ---- workspace layout (~140.7 MB) ----
    float* gb1   = (float*)d_ws;             // 4096
    float* betab = gb1 + 4096;
    float* gateb = betab + 4096;
    float* kbuf  = gateb + 4096;             // 8192
    float* vbuf  = kbuf + 8192;
    float* bqp   = vbuf + 8192;              // 512
    float* sfac  = bqp + 512;                // 512
    float* hbuf  = sfac + 512;               // 4096
    float* tokbuf= hbuf + 4096;              // 8192
    float* stats = tokbuf + 8192;            // 65536
    u16* ctxbf = (u16*)(stats + 65536);      // 2048
    u16* cwbf  = ctxbf + 2048;               // 393216
    u16* wqbf  = cwbf + 393216;              // 262144
    u16* owbf  = wqbf + 262144;              // 262144
    u16* m1bf  = owbf + 262144;              // 1572864
    u16* m2bf  = m1bf + 1572864;             // 524288
    u16* bufc  = m2bf + 524288;              // U2: 16777216  upd_c
    u16* q_ao  = bufc + 16777216;            // U3: q -> ao -> upd_a
    u16* xbf_a = q_ao + 16777216;            // U1: xbf -> a -> bufh lower
    u16* bufh  = xbf_a;                      // spans U1+U4 (33554432 elems)

    // ---- context path (parallel, wave-per-output) ----
    ctx_stage_a<<<4096, 256, 0, stream>>>(context, film_w, film_b, gate_w, gate_b,
                                          ctx_w1, ctx_b1, gb1, betab, gateb, hbuf, ctxbf);
    ctx_stage_b<<<2048, 256, 0, stream>>>(hbuf, ctx_w2, ctx_b2, tokbuf);
    ctx_stage_c<<<4096, 256, 0, stream>>>(tokbuf, in_proj_w, in_proj_b, kbuf, vbuf);

    foldq_kernel<<<128, 256, 0, stream>>>(in_proj_w, in_proj_b, q_ln_g, q_ln_b,
                                          wqbf, bqp, sfac);
    wconv_kernel<<<192, 256, 0, stream>>>(concat_w, cwbf, 49152);
    wconv_kernel<<<128, 256, 0, stream>>>(out_proj_w, owbf, 32768);
    wconv_kernel<<<256, 256, 0, stream>>>(mix_w2, m2bf, 65536);
    wmix1_kernel<<<768, 256, 0, stream>>>(mix_w1, m1bf);
    stats_kernel<<<N_TOK / 4, 256, 0, stream>>>(x, stats, xbf_a);

    // concat: relu([x|ctx] @ concat_w^T + b) -> bufc, then LN
    mfma_gemm<1, 0, true><<<dim3(256, 4), 256, 0, stream>>>(
        xbf_a, ctxbf, nullptr, cwbf, concat_b, nullptr, nullptr, bufc, 768, 512);
    lnrows_kernel<<<N_TOK / 4, 256, 0, stream>>>(bufc, concat_ln_g, concat_ln_b);

    // q = rstd*(x @ W'^T - mean*s) + b' -> q_ao
    mfma_gemm<0, 1, false><<<dim3(256, 4), 256, 0, stream>>>(
        xbf_a, nullptr, nullptr, wqbf, bqp, stats, sfac, q_ao, 512, 512);
    attn_kernel<<<N_TOK / 4, 256, 0, stream>>>(q_ao, kbuf, vbuf, xbf_a);  // a -> U1
    // ao = a @ out_proj^T + b -> q_ao (q dead)
    mfma_gemm<0, 0, false><<<dim3(256, 4), 256, 0, stream>>>(
        xbf_a, nullptr, nullptr, owbf, out_proj_b, nullptr, nullptr, q_ao, 512, 512);

    // h = relu([x|ao|x*ao] @ W1'^T + b) -> bufh (U1+U4; a dead)
    mfma_gemm<2, 0, true><<<dim3(256, 8), 256, 0, stream>>>(
        nullptr, q_ao, x, m1bf, mix_b1, nullptr, nullptr, bufh, 1536, 1024);
    // upd_a = h @ mix_w2^T + b -> q_ao (ao dead)
    mfma_gemm<0, 0, false><<<dim3(256, 4), 256, 0, stream>>>(
        bufh, nullptr, nullptr, m2bf, mix_b2, nullptr, nullptr, q_ao, 1024, 512);

    final_kernel<<<N_TOK / 4, 256, 0, stream>>>(x, stats, bufc, q_ao,
                                                gb1, betab, gateb, mask,
                                                film_ln_g, film_ln_b,
                                                out_ln_g, out_ln_b, out);
    (void)in_sizes; (void)n_in; (void)out_size; (void)ws_size;
}

// Round 4
// 532.445 us; speedup vs baseline: 7.4718x; 1.1856x over previous
//
#include <hip/hip_runtime.h>
#include <hip/hip_bf16.h>

// HybridBridge round 4: attention branch eliminated algebraically (T=2 ->
// rank-4 update), XOR-swizzled LDS (conflict-free MFMA fragment reads),
// LDS-transposed vectorized GEMM epilogue, mix GEMMs split in row-halves.
// B=8, L=4096, D=512, C=256, T=2, H=2, HD=256. N = 32768 rows.

#define N_TOK 32768

typedef unsigned short u16;
typedef __attribute__((ext_vector_type(8))) __bf16 bf16x8;
typedef __attribute__((ext_vector_type(4))) float f32x4;

__device__ __forceinline__ float bf2f(unsigned int h) { return __uint_as_float(h << 16); }
__device__ __forceinline__ u16 f2bf(float f) {
    unsigned int u = __float_as_uint(f);
    u += 0x7FFFu + ((u >> 16) & 1u);   // RNE
    return (u16)(u >> 16);
}
__device__ __forceinline__ void load8(const u16* p, float* v) {
    uint4 u = *(const uint4*)p;
    v[0] = bf2f(u.x & 0xffffu); v[1] = bf2f(u.x >> 16);
    v[2] = bf2f(u.y & 0xffffu); v[3] = bf2f(u.y >> 16);
    v[4] = bf2f(u.z & 0xffffu); v[5] = bf2f(u.z >> 16);
    v[6] = bf2f(u.w & 0xffffu); v[7] = bf2f(u.w >> 16);
}
__device__ __forceinline__ uint4 pack8(const float* v) {
    uint4 u;
    u.x = (unsigned)f2bf(v[0]) | ((unsigned)f2bf(v[1]) << 16);
    u.y = (unsigned)f2bf(v[2]) | ((unsigned)f2bf(v[3]) << 16);
    u.z = (unsigned)f2bf(v[4]) | ((unsigned)f2bf(v[5]) << 16);
    u.w = (unsigned)f2bf(v[6]) | ((unsigned)f2bf(v[7]) << 16);
    return u;
}
__device__ __forceinline__ void async16(const u16* g, u16* lds) {
    __builtin_amdgcn_global_load_lds(
        (const __attribute__((address_space(1))) unsigned int*)g,
        (__attribute__((address_space(3))) unsigned int*)lds, 16, 0, 0);
}

// ==== context stage A: film gamma/beta, gate, gelu(h). wave-per-output ===
__global__ void ctx_stage_a(const float* __restrict__ context,
                            const float* __restrict__ film_w, const float* __restrict__ film_b,
                            const float* __restrict__ gate_w, const float* __restrict__ gate_b,
                            const float* __restrict__ ctx_w1, const float* __restrict__ ctx_b1,
                            float* __restrict__ gb1, float* __restrict__ betab,
                            float* __restrict__ gateb, float* __restrict__ hbuf,
                            u16* __restrict__ ctxbf) {
    if (blockIdx.x == 0) {
        for (int i = threadIdx.x; i < 2048; i += 256)
            ctxbf[i] = f2bf(context[i]);
    }
    const int wave = threadIdx.x >> 6, lane = threadIdx.x & 63;
    const int widx = blockIdx.x * 4 + wave;       // 0..16383
    const int b   = widx >> 11;
    const int j2  = widx & 2047;
    const int cat = j2 >> 9;
    const int j   = j2 & 511;
    const float* wrow;
    if      (cat == 0) wrow = film_w + (size_t)j * 256;
    else if (cat == 1) wrow = film_w + (size_t)(512 + j) * 256;
    else if (cat == 2) wrow = gate_w + (size_t)j * 256;
    else               wrow = ctx_w1 + (size_t)j * 256;
    float4 wv = *(const float4*)(wrow + lane * 4);
    float4 cv = *(const float4*)(context + b * 256 + lane * 4);
    float s = wv.x * cv.x + wv.y * cv.y + wv.z * cv.z + wv.w * cv.w;
    for (int m = 1; m < 64; m <<= 1) s += __shfl_xor(s, m, 64);
    if (lane == 0) {
        if      (cat == 0) gb1[b * 512 + j]   = 1.0f + s + film_b[j];
        else if (cat == 1) betab[b * 512 + j] = s + film_b[512 + j];
        else if (cat == 2) gateb[b * 512 + j] = 1.f / (1.f + expf(-(s + gate_b[j])));
        else {
            float hv = s + ctx_b1[j];
            hbuf[b * 512 + j] = 0.5f * hv * (1.0f + erff(hv * 0.70710678118654752f));
        }
    }
}

// ==== context stage B: ctx_tok = h @ ctx_w2^T + b2 =======================
__global__ void ctx_stage_b(const float* __restrict__ hbuf,
                            const float* __restrict__ ctx_w2, const float* __restrict__ ctx_b2,
                            float* __restrict__ tokbuf) {
    const int wave = threadIdx.x >> 6, lane = threadIdx.x & 63;
    const int widx = blockIdx.x * 4 + wave;       // 0..8191
    const int b = widx >> 10;
    const int j = widx & 1023;
    const float* wrow = ctx_w2 + (size_t)j * 512 + lane * 8;
    const float* hr   = hbuf + b * 512 + lane * 8;
    float4 w0 = *(const float4*)wrow, w1 = *(const float4*)(wrow + 4);
    float4 h0 = *(const float4*)hr,   h1 = *(const float4*)(hr + 4);
    float s = w0.x*h0.x + w0.y*h0.y + w0.z*h0.z + w0.w*h0.w
            + w1.x*h1.x + w1.y*h1.y + w1.z*h1.z + w1.w*h1.w;
    for (int m = 1; m < 64; m <<= 1) s += __shfl_xor(s, m, 64);
    if (lane == 0) tokbuf[b * 1024 + j] = s + ctx_b2[j];
}

// ==== context stage C: k,v = tok @ wk/wv^T + b ===========================
__global__ void ctx_stage_c(const float* __restrict__ tokbuf,
                            const float* __restrict__ in_proj_w, const float* __restrict__ in_proj_b,
                            float* __restrict__ kbuf, float* __restrict__ vbuf) {
    const int wave = threadIdx.x >> 6, lane = threadIdx.x & 63;
    const int widx = blockIdx.x * 4 + wave;       // 0..16383
    const int b  = widx >> 11;
    const int r  = widx & 2047;
    const int t  = r >> 10;
    const int kv = (r >> 9) & 1;
    const int j  = r & 511;
    const float* wrow = in_proj_w + (size_t)(512 + kv * 512 + j) * 512 + lane * 8;
    const float* tk   = tokbuf + (b * 2 + t) * 512 + lane * 8;
    float4 w0 = *(const float4*)wrow, w1 = *(const float4*)(wrow + 4);
    float4 t0 = *(const float4*)tk,   t1 = *(const float4*)(tk + 4);
    float s = w0.x*t0.x + w0.y*t0.y + w0.z*t0.z + w0.w*t0.w
            + w1.x*t1.x + w1.y*t1.y + w1.z*t1.z + w1.w*t1.w;
    for (int m = 1; m < 64; m <<= 1) s += __shfl_xor(s, m, 64);
    if (lane == 0) {
        float v = s + in_proj_b[512 + kv * 512 + j];
        if (kv == 0) kbuf[(b * 2 + t) * 512 + j] = v;
        else         vbuf[(b * 2 + t) * 512 + j] = v;
    }
}

// ==== bqp[j] = bq[j] + Wq[j,:] . q_ln_b  (wave-per-j) ====================
__global__ void foldq_kernel(const float* __restrict__ in_proj_w,
                             const float* __restrict__ in_proj_b,
                             const float* __restrict__ qb, float* __restrict__ bqp) {
    const int wave = threadIdx.x >> 6, lane = threadIdx.x & 63;
    const int j = blockIdx.x * 4 + wave;          // 0..511
    const int i = lane * 8;
    float4 w0 = *(const float4*)(in_proj_w + (size_t)j * 512 + i);
    float4 w1 = *(const float4*)(in_proj_w + (size_t)j * 512 + i + 4);
    float4 b0 = *(const float4*)(qb + i);
    float4 b1 = *(const float4*)(qb + i + 4);
    float p1 = w0.x*b0.x + w0.y*b0.y + w0.z*b0.z + w0.w*b0.w
             + w1.x*b1.x + w1.y*b1.y + w1.z*b1.z + w1.w*b1.w;
    for (int m = 1; m < 64; m <<= 1) p1 += __shfl_xor(p1, m, 64);
    if (lane == 0) bqp[j] = in_proj_b[j] + p1;
}

// ==== context stage D: u/su/c0 (bid<32) and vo (bid>=32) =================
// flat idx = b*4 + t*2 + h
__global__ void ctx_stage_d(const float* __restrict__ in_proj_w,
                            const float* __restrict__ out_proj_w,
                            const float* __restrict__ qg, const float* __restrict__ bqp,
                            const float* __restrict__ kbuf, const float* __restrict__ vbuf,
                            float* __restrict__ ubuf, float* __restrict__ vobuf,
                            float* __restrict__ subuf, float* __restrict__ c0buf) {
    const int tid = threadIdx.x;
    __shared__ float sh[256];
    __shared__ float red[256];
    if (blockIdx.x < 32) {
        const int bid = blockIdx.x;
        const int b = bid >> 2, idx = bid & 3;
        const int t = idx >> 1, h = idx & 1;
        sh[tid] = kbuf[(b * 2 + t) * 512 + h * 256 + tid];
        __syncthreads();
        float a0 = 0.f, a1 = 0.f;
        #pragma unroll 4
        for (int dd = 0; dd < 256; dd++) {
            const float kv = sh[dd];
            const float* wr = in_proj_w + (size_t)(h * 256 + dd) * 512;
            a0 += kv * wr[tid];
            a1 += kv * wr[tid + 256];
        }
        float u0 = a0 * qg[tid], u1 = a1 * qg[tid + 256];
        ubuf[bid * 512 + tid]       = u0;
        ubuf[bid * 512 + tid + 256] = u1;
        red[tid] = u0 + u1;
        __syncthreads();
        for (int s = 128; s > 0; s >>= 1) { if (tid < s) red[tid] += red[tid + s]; __syncthreads(); }
        if (tid == 0) subuf[bid] = red[0];
        __syncthreads();
        red[tid] = bqp[h * 256 + tid] * sh[tid];
        __syncthreads();
        for (int s = 128; s > 0; s >>= 1) { if (tid < s) red[tid] += red[tid + s]; __syncthreads(); }
        if (tid == 0) c0buf[bid] = red[0];
    } else {
        const int bid = blockIdx.x - 32;
        const int b = bid >> 2, idx = bid & 3;
        const int t = idx >> 1, h = idx & 1;
        sh[tid] = vbuf[(b * 2 + t) * 512 + h * 256 + tid];
        __syncthreads();
        const float* w0 = out_proj_w + (size_t)tid * 512 + h * 256;
        const float* w1 = out_proj_w + (size_t)(tid + 256) * 512 + h * 256;
        float acc0 = 0.f, acc1 = 0.f;
        #pragma unroll 2
        for (int dd = 0; dd < 256; dd += 4) {
            float4 x0 = *(const float4*)(w0 + dd);
            float4 x1 = *(const float4*)(w1 + dd);
            acc0 += x0.x*sh[dd] + x0.y*sh[dd+1] + x0.z*sh[dd+2] + x0.w*sh[dd+3];
            acc1 += x1.x*sh[dd] + x1.y*sh[dd+1] + x1.z*sh[dd+2] + x1.w*sh[dd+3];
        }
        vobuf[bid * 512 + tid]       = acc0;
        vobuf[bid * 512 + tid + 256] = acc1;
    }
}

// ==== generic fp32 -> bf16 weight convert ================================
__global__ void wconv_kernel(const float* __restrict__ src, u16* __restrict__ dst, int n8) {
    int i = blockIdx.x * blockDim.x + threadIdx.x;
    if (i >= n8) return;
    const float* s = src + (size_t)i * 8;
    float4 a = *(const float4*)s;
    float4 b = *(const float4*)(s + 4);
    float v[8] = {a.x, a.y, a.z, a.w, b.x, b.y, b.z, b.w};
    *(uint4*)(dst + (size_t)i * 8) = pack8(v);
}

// ==== build mix W': [Wa+Wc | Wb-Wc | Wd] 1024x1536 bf16 ==================
__global__ void wmix1_kernel(const float* __restrict__ W1, u16* __restrict__ dst) {
    int idx = blockIdx.x * 256 + threadIdx.x;      // < 196608
    int n = idx / 192;
    int k = (idx - n * 192) * 8;
    const float* base = W1 + (size_t)n * 2048;
    float v[8];
    if (k < 512) {
        #pragma unroll
        for (int e = 0; e < 8; e++) v[e] = base[k + e] + base[1024 + k + e];
    } else if (k < 1024) {
        #pragma unroll
        for (int e = 0; e < 8; e++) v[e] = base[k + e] - base[512 + k + e];
    } else {
        #pragma unroll
        for (int e = 0; e < 8; e++) v[e] = base[512 + k + e];
    }
    *(uint4*)(dst + (size_t)n * 1536 + k) = pack8(v);
}

// ==== per-row mean/rstd of x + x->bf16 into mixA (ld 1024) ===============
__global__ void stats_kernel(const float* __restrict__ x, float* __restrict__ stats,
                             u16* __restrict__ mixA) {
    const int wave = threadIdx.x >> 6, lane = threadIdx.x & 63;
    const size_t row = (size_t)blockIdx.x * 4 + wave;
    const float* xr = x + row * 512 + lane * 8;
    float4 a = *(const float4*)xr;
    float4 b = *(const float4*)(xr + 4);
    float v[8] = {a.x, a.y, a.z, a.w, b.x, b.y, b.z, b.w};
    float s = 0.f, ss = 0.f;
    #pragma unroll
    for (int e = 0; e < 8; e++) { s += v[e]; ss += v[e] * v[e]; }
    for (int m = 1; m < 64; m <<= 1) { s += __shfl_xor(s, m, 64); ss += __shfl_xor(ss, m, 64); }
    *(uint4*)(mixA + row * 1024 + lane * 8) = pack8(v);
    float mean = s * (1.f / 512.f);
    float var  = ss * (1.f / 512.f) - mean * mean;
    if (lane == 0) { stats[row * 2] = mean; stats[row * 2 + 1] = rsqrtf(var + 1e-5f); }
}

// ==== MFMA GEMM, XOR-swizzled LDS, vectorized LDS-transpose epilogue =====
// AMODE 0: A = A0 (bf16, leading dim lda)
// AMODE 1: A = [A0(xbf, ld 1024) | A1(ctxbf, per-batch broadcast)], K=768
// AMODE 2: A = mixA [x | ao | x*ao], K=1536 (segs 0-1 async, seg 2 VALU)
template<int AMODE, bool RELU>
__launch_bounds__(256)
__global__ void mfma_gemm(const u16* __restrict__ A0, const u16* __restrict__ A1,
                          const u16* __restrict__ Wb, const float* __restrict__ bias,
                          u16* __restrict__ out, const int K, const int lda, const int ldo) {
    __shared__ __align__(16) u16 S[16384];
    u16* As = S;
    u16* Bs = S + 8192;
    const int tid = threadIdx.x;
    const int w = tid >> 6, l = tid & 63;
    const int wm = w >> 1, wn = w & 1;
    const size_t m0 = (size_t)blockIdx.x * 128;
    const int n0 = blockIdx.y * 128;
    const int rb = w * 8 + (l >> 3);              // staging row base 0..31
    const int kswz = ((l & 7) ^ (l >> 3)) * 8;    // XOR-swizzled k offset
    const int bidx = (int)(m0 >> 12);
    const int quad = l >> 4, lc = l & 15;

    f32x4 acc[4][4];
    #pragma unroll
    for (int i = 0; i < 4; i++)
        #pragma unroll
        for (int j = 0; j < 4; j++) acc[i][j] = (f32x4){0.f, 0.f, 0.f, 0.f};

    for (int k0 = 0; k0 < K; k0 += 64) {
        __syncthreads();
        // ---- stage A tile 128x64 (swizzled chunks) ----
        if constexpr (AMODE == 0) {
            #pragma unroll
            for (int r = 0; r < 4; r++)
                async16(A0 + (m0 + r * 32 + rb) * (size_t)lda + k0 + kswz, &As[r * 2048 + w * 512]);
        } else if constexpr (AMODE == 1) {
            if (k0 < 512) {
                #pragma unroll
                for (int r = 0; r < 4; r++)
                    async16(A0 + (m0 + r * 32 + rb) * (size_t)lda + k0 + kswz, &As[r * 2048 + w * 512]);
            } else {
                #pragma unroll
                for (int r = 0; r < 4; r++)
                    async16(A1 + bidx * 256 + (k0 - 512) + kswz, &As[r * 2048 + w * 512]);
            }
        } else {
            if (k0 < 1024) {       // [x | ao] both contiguous in mixA
                #pragma unroll
                for (int r = 0; r < 4; r++)
                    async16(A0 + (m0 + r * 32 + rb) * (size_t)1024 + k0 + kswz, &As[r * 2048 + w * 512]);
            } else {               // x * ao on the fly (bf16 inputs)
                #pragma unroll
                for (int r = 0; r < 4; r++) {
                    const int row = r * 32 + rb;
                    const u16* g = A0 + (m0 + row) * (size_t)1024 + (k0 - 1024) + kswz;
                    float xv[8], av[8];
                    load8(g, xv); load8(g + 512, av);
                    float pv[8] = {xv[0]*av[0], xv[1]*av[1], xv[2]*av[2], xv[3]*av[3],
                                   xv[4]*av[4], xv[5]*av[5], xv[6]*av[6], xv[7]*av[7]};
                    *(uint4*)&As[r * 2048 + w * 512 + l * 8] = pack8(pv);
                }
            }
        }
        // ---- stage B tile 128x64 ----
        #pragma unroll
        for (int r = 0; r < 4; r++)
            async16(Wb + (size_t)(n0 + r * 32 + rb) * K + k0 + kswz, &Bs[r * 2048 + w * 512]);
        __syncthreads();
        // ---- compute ----
        #pragma unroll
        for (int kk = 0; kk < 2; kk++) {
            bf16x8 af[4], bff[4];
            #pragma unroll
            for (int t = 0; t < 4; t++) {
                const int ch = ((kk << 2) | quad) ^ (lc & 7);
                af[t]  = *(const bf16x8*)&As[(wm * 64 + t * 16 + lc) * 64 + ch * 8];
                bff[t] = *(const bf16x8*)&Bs[(wn * 64 + t * 16 + lc) * 64 + ch * 8];
            }
            #pragma unroll
            for (int i = 0; i < 4; i++)
                #pragma unroll
                for (int j = 0; j < 4; j++)
                    acc[i][j] = __builtin_amdgcn_mfma_f32_16x16x32_bf16(af[i], bff[j], acc[i][j], 0, 0, 0);
        }
    }

    // ---- epilogue: bias/relu -> LDS (64x136 pad) -> coalesced b128 stores
    float bv[4];
    #pragma unroll
    for (int j = 0; j < 4; j++) bv[j] = bias[n0 + wn * 64 + j * 16 + lc];
    const int erow = tid >> 2;           // 0..63
    const int ecb  = (tid & 3) * 32;
    __syncthreads();
    #pragma unroll
    for (int p = 0; p < 2; p++) {
        if (p) __syncthreads();
        if (wm == p) {
            #pragma unroll
            for (int i = 0; i < 4; i++)
                #pragma unroll
                for (int j = 0; j < 4; j++)
                    #pragma unroll
                    for (int reg = 0; reg < 4; reg++) {
                        float vv = acc[i][j][reg] + bv[j];
                        if (RELU) vv = fmaxf(vv, 0.f);
                        S[(i * 16 + quad * 4 + reg) * 136 + wn * 64 + j * 16 + lc] = f2bf(vv);
                    }
        }
        __syncthreads();
        #pragma unroll
        for (int q = 0; q < 4; q++)
            *(uint4*)(out + (m0 + p * 64 + erow) * (size_t)ldo + n0 + ecb + q * 8)
                = *(const uint4*)&S[erow * 136 + ecb + q * 8];
    }
}

// ==== row LayerNorm on bf16 buffer (in place, ld 512) ====================
__global__ void lnrows_kernel(u16* __restrict__ buf,
                              const float* __restrict__ g, const float* __restrict__ b) {
    const int wave = threadIdx.x >> 6, lane = threadIdx.x & 63;
    const size_t row = (size_t)blockIdx.x * 4 + wave;
    u16* p = buf + row * 512 + lane * 8;
    float v[8];
    load8(p, v);
    float s = 0.f, ss = 0.f;
    #pragma unroll
    for (int e = 0; e < 8; e++) { s += v[e]; ss += v[e] * v[e]; }
    for (int m = 1; m < 64; m <<= 1) { s += __shfl_xor(s, m, 64); ss += __shfl_xor(ss, m, 64); }
    float mean = s * (1.f / 512.f);
    float rstd = rsqrtf(ss * (1.f / 512.f) - mean * mean + 1e-5f);
    float o[8];
    #pragma unroll
    for (int e = 0; e < 8; e++) {
        int c = lane * 8 + e;
        o[e] = (v[e] - mean) * rstd * g[c] + b[c];
    }
    *(uint4*)p = pack8(o);
}

// ==== attn-lite: scores from u/su/c0, ao = sum p*vo + ob -> mixA[:,512:] =
__global__ void attn_lite(const u16* __restrict__ mixA_r, u16* __restrict__ mixA_w,
                          const float* __restrict__ stats,
                          const float* __restrict__ ubuf, const float* __restrict__ subuf,
                          const float* __restrict__ c0buf, const float* __restrict__ vobuf,
                          const float* __restrict__ ob) {
    const int wave = threadIdx.x >> 6, lane = threadIdx.x & 63;
    const size_t row = (size_t)blockIdx.x * 4 + wave;
    const int b = (int)(row >> 12);
    float v[8];
    load8(mixA_r + row * 1024 + lane * 8, v);
    const float mean = stats[row * 2], rstd = stats[row * 2 + 1];
    float s[4];
    #pragma unroll
    for (int idx = 0; idx < 4; idx++) {
        const float* u = ubuf + (b * 4 + idx) * 512 + lane * 8;
        float4 u0 = *(const float4*)u, u1 = *(const float4*)(u + 4);
        s[idx] = v[0]*u0.x + v[1]*u0.y + v[2]*u0.z + v[3]*u0.w
               + v[4]*u1.x + v[5]*u1.y + v[6]*u1.z + v[7]*u1.w;
    }
    for (int m = 1; m < 64; m <<= 1) {
        #pragma unroll
        for (int idx = 0; idx < 4; idx++) s[idx] += __shfl_xor(s[idx], m, 64);
    }
    float sc[4];
    #pragma unroll
    for (int idx = 0; idx < 4; idx++)
        sc[idx] = (rstd * (s[idx] - mean * subuf[b * 4 + idx]) + c0buf[b * 4 + idx]) * (1.f / 16.f);
    float p[4];
    #pragma unroll
    for (int h = 0; h < 2; h++) {
        float s0 = sc[h], s1 = sc[2 + h];          // t=0, t=1
        float mx = fmaxf(s0, s1);
        float e0 = expf(s0 - mx), e1 = expf(s1 - mx);
        float inv = 1.f / (e0 + e1);
        p[h] = e0 * inv; p[2 + h] = e1 * inv;
    }
    const float* vo0 = vobuf + (b * 4 + 0) * 512 + lane * 8;
    const float* vo1 = vobuf + (b * 4 + 1) * 512 + lane * 8;
    const float* vo2 = vobuf + (b * 4 + 2) * 512 + lane * 8;
    const float* vo3 = vobuf + (b * 4 + 3) * 512 + lane * 8;
    const float* obp = ob + lane * 8;
    float o[8];
    #pragma unroll
    for (int e = 0; e < 8; e++)
        o[e] = p[0]*vo0[e] + p[1]*vo1[e] + p[2]*vo2[e] + p[3]*vo3[e] + obp[e];
    *(uint4*)(mixA_w + row * 1024 + 512 + lane * 8) = pack8(o);
}

// ==== final: LN(base + gate*mask*(upd_c+upd_a)) ==========================
__global__ void final_kernel(const u16* __restrict__ mixA, const float* __restrict__ stats,
                             const u16* __restrict__ updc,
                             const float* __restrict__ gb1, const float* __restrict__ betab,
                             const float* __restrict__ gateb, const int* __restrict__ mask,
                             const float* __restrict__ fg, const float* __restrict__ fb,
                             const float* __restrict__ og, const float* __restrict__ ob,
                             float* __restrict__ out) {
    const int wave = threadIdx.x >> 6, lane = threadIdx.x & 63;
    const size_t row = (size_t)blockIdx.x * 4 + wave;
    const int b = (int)(row >> 12);
    const int c0 = lane * 8;
    float xv[8], uc[8], ua[8];
    load8(mixA + row * 1024 + c0, xv);          // xbf
    load8(mixA + row * 1024 + 512 + c0, ua);    // upd_a
    load8(updc + row * 512 + c0, uc);
    const float mean = stats[row * 2], rstd = stats[row * 2 + 1];
    const float mf = (mask[row] != 0) ? 1.f : 0.f;
    float y[8];
    float s = 0.f, ss = 0.f;
    #pragma unroll
    for (int e = 0; e < 8; e++) {
        int c = c0 + e;
        float xh = (xv[e] - mean) * rstd;
        float base = gb1[b * 512 + c] * (xh * fg[c] + fb[c]) + betab[b * 512 + c];
        float yv = base + gateb[b * 512 + c] * mf * (uc[e] + ua[e]);
        y[e] = yv; s += yv; ss += yv * yv;
    }
    for (int m = 1; m < 64; m <<= 1) { s += __shfl_xor(s, m, 64); ss += __shfl_xor(ss, m, 64); }
    float mean2 = s * (1.f / 512.f);
    float rstd2 = rsqrtf(ss * (1.f / 512.f) - mean2 * mean2 + 1e-5f);
    float o[8];
    #pragma unroll
    for (int e = 0; e < 8; e++) {
        int c = c0 + e;
        o[e] = (y[e] - mean2) * rstd2 * og[c] + ob[c];
    }
    *(float4*)(out + row * 512 + c0)     = make_float4(o[0], o[1], o[2], o[3]);
    *(float4*)(out + row * 512 + c0 + 4) = make_float4(o[4], o[5], o[6], o[7]);
}

extern "C" void kernel_launch(void* const* d_in, const int* in_sizes, int n_in,
                              void* d_out, int out_size, void* d_ws, size_t ws_size,
                              hipStream_t stream) {
    const float* x          = (const float*)d_in[0];
    const float* context    = (const float*)d_in[1];
    const int*   mask       = (const int*)d_in[2];
    const float* film_ln_g  = (const float*)d_in[3];
    const float* film_ln_b  = (const float*)d_in[4];
    const float* film_w     = (const float*)d_in[5];
    const float* film_b     = (const float*)d_in[6];
    const float* concat_w   = (const float*)d_in[7];
    const float* concat_b   = (const float*)d_in[8];
    const float* concat_ln_g= (const float*)d_in[9];
    const float* concat_ln_b= (const float*)d_in[10];
    const float* ctx_w1     = (const float*)d_in[11];
    const float* ctx_b1     = (const float*)d_in[12];
    const float* ctx_w2     = (const float*)d_in[13];
    const float* ctx_b2     = (const float*)d_in[14];
    const float* q_ln_g     = (const float*)d_in[15];
    const float* q_ln_b     = (const float*)d_in[16];
    const float* in_proj_w  = (const float*)d_in[17];
    const float* in_proj_b  = (const float*)d_in[18];
    const float* out_proj_w = (const float*)d_in[19];
    const float* out_proj_b = (const float*)d_in[20];
    const float* mix_w1     = (const float*)d_in[21];
    const float* mix_b1     = (const float*)d_in[22];
    const float* mix_w2     = (const float*)d_in[23];
    const float* mix_b2     = (const float*)d_in[24];
    const float* out_ln_g   = (const float*)d_in[25];
    const float* out_ln_b   = (const float*)d_in[26];
    const float* gate_w     = (const float*)d_in[27];
    const float* gate_b     = (const float*)d_in[28];
    float* out = (float*)d_out;

    // ---- workspace layout (~133.5 MB) ----
    float* gb1    = (float*)d_ws;            // 4096
    float* betab  = gb1 + 4096;
    float* gateb  = betab + 4096;
    float* kbuf   = gateb + 4096;            // 8192
    float* vbuf   = kbuf + 8192;
    float* bqp    = vbuf + 8192;             // 512
    float* hbuf   = bqp + 512;               // 4096
    float* tokbuf = hbuf + 4096;             // 8192
    float* ubuf   = tokbuf + 8192;           // 16384
    float* vobuf  = ubuf + 16384;            // 16384
    float* subuf  = vobuf + 16384;           // 32
    float* c0buf  = subuf + 32;              // 32
    float* stats  = c0buf + 32;              // 65536
    u16* ctxbf = (u16*)(stats + 65536);      // 2048
    u16* cwbf  = ctxbf + 2048;               // 393216
    u16* m1bf  = cwbf + 393216;              // 1572864
    u16* m2bf  = m1bf + 1572864;             // 524288
    u16* mixA  = m2bf + 524288;              // 32768*1024 [xbf | ao->upd_a]
    u16* bufc  = mixA + (size_t)N_TOK * 1024;   // 32768*512 upd_c
    u16* bufh  = bufc + (size_t)N_TOK * 512;    // 16384*1024 (half, reused)

    // ---- context path ----
    ctx_stage_a<<<4096, 256, 0, stream>>>(context, film_w, film_b, gate_w, gate_b,
                                          ctx_w1, ctx_b1, gb1, betab, gateb, hbuf, ctxbf);
    ctx_stage_b<<<2048, 256, 0, stream>>>(hbuf, ctx_w2, ctx_b2, tokbuf);
    ctx_stage_c<<<4096, 256, 0, stream>>>(tokbuf, in_proj_w, in_proj_b, kbuf, vbuf);
    foldq_kernel<<<128, 256, 0, stream>>>(in_proj_w, in_proj_b, q_ln_b, bqp);
    ctx_stage_d<<<64, 256, 0, stream>>>(in_proj_w, out_proj_w, q_ln_g, bqp,
                                        kbuf, vbuf, ubuf, vobuf, subuf, c0buf);

    wconv_kernel<<<192, 256, 0, stream>>>(concat_w, cwbf, 49152);
    wconv_kernel<<<256, 256, 0, stream>>>(mix_w2, m2bf, 65536);
    wmix1_kernel<<<768, 256, 0, stream>>>(mix_w1, m1bf);
    stats_kernel<<<N_TOK / 4, 256, 0, stream>>>(x, stats, mixA);

    // concat: relu([x|ctx] @ concat_w^T + b) -> bufc, then LN -> upd_c
    mfma_gemm<1, true><<<dim3(256, 4), 256, 0, stream>>>(
        mixA, ctxbf, cwbf, concat_b, bufc, 768, 1024, 512);
    lnrows_kernel<<<N_TOK / 4, 256, 0, stream>>>(bufc, concat_ln_g, concat_ln_b);

    // attention (algebraic): ao -> mixA[:, 512:1024]
    attn_lite<<<N_TOK / 4, 256, 0, stream>>>(mixA, mixA, stats, ubuf, subuf,
                                             c0buf, vobuf, out_proj_b);

    // mix MLP in two row-halves (bufh is half-sized, reused)
    const size_t halfA = (size_t)16384 * 1024;
    // half 1
    mfma_gemm<2, true><<<dim3(128, 8), 256, 0, stream>>>(
        mixA, nullptr, m1bf, mix_b1, bufh, 1536, 1024, 1024);
    mfma_gemm<0, false><<<dim3(128, 4), 256, 0, stream>>>(
        bufh, nullptr, m2bf, mix_b2, mixA + 512, 1024, 1024, 1024);
    // half 2
    mfma_gemm<2, true><<<dim3(128, 8), 256, 0, stream>>>(
        mixA + halfA, nullptr, m1bf, mix_b1, bufh, 1536, 1024, 1024);
    mfma_gemm<0, false><<<dim3(128, 4), 256, 0, stream>>>(
        bufh, nullptr, m2bf, mix_b2, mixA + 512 + halfA, 1024, 1024, 1024);

    final_kernel<<<N_TOK / 4, 256, 0, stream>>>(mixA, stats, bufc,
                                                gb1, betab, gateb, mask,
                                                film_ln_g, film_ln_b,
                                                out_ln_g, out_ln_b, out);
    (void)in_sizes; (void)n_in; (void)out_size; (void)ws_size; (void)q_ln_g;
}